// Round 4
// baseline (795.658 us; speedup 1.0000x reference)
//
#include <hip/hip_runtime.h>
#include <math.h>

typedef unsigned short u16;
typedef unsigned int u32;
typedef __attribute__((ext_vector_type(8))) short bf16x8;
typedef __attribute__((ext_vector_type(4))) float f32x4;

constexpr int Bc = 32, Nc = 1024, Cc = 768, Hc = 12, HDc = 64, Mc = 128;
constexpr int NUM_STEP_C = 8;
constexpr float QSCALE = 0.35355339059327376f;      // 8^-0.5
constexpr float INV_SQRT_M = 0.088388347648318447f; // 1/sqrt(128)
constexpr float EPSC = 1e-12f;

__device__ __forceinline__ float softf(float z, float thr) {
  float az = fabsf(z) - thr;
  float g = 0.5f * az * (1.0f + erff(az * 0.70710678118654752f));
  return (z > 0.f) ? g : ((z < 0.f) ? -g : 0.f);
}

__device__ __forceinline__ u16 f2bf(float f) {
  u32 u = __float_as_uint(f);
  u += 0x7fffu + ((u >> 16) & 1u);
  return (u16)(u >> 16);
}

__device__ __forceinline__ f32x4 fzero() {
  f32x4 z; z[0] = 0.f; z[1] = 0.f; z[2] = 0.f; z[3] = 0.f; return z;
}

__device__ __forceinline__ f32x4 mfma16(bf16x8 a, bf16x8 b, f32x4 c) {
  return __builtin_amdgcn_mfma_f32_16x16x32_bf16(a, b, c, 0, 0, 0);
}

// Stage 32 rows x 64 u16 (128 B/row) of a row-major (ld elems) global tile
// into linear LDS [128][64], rows [w*32, w*32+32), via global_load_lds.
// LDS dest is wave-uniform base; HW adds lane*16B. Global src is per-lane.
__device__ __forceinline__ void stage_gll(const u16* __restrict__ g, int ld,
                                          u16* lds, int w, int lane) {
#pragma unroll
  for (int c = 0; c < 4; ++c) {
    const int r0 = w * 32 + c * 8;
    const u16* src = g + (size_t)(r0 + (lane >> 3)) * ld + (lane & 7) * 8;
    u16* dst = lds + r0 * 64;
    __builtin_amdgcn_global_load_lds(
        (const __attribute__((address_space(1))) void*)src,
        (__attribute__((address_space(3))) void*)dst, 16, 0, 0);
  }
}

// ---------------------------------------------------------------------------
// prep: f32 -> bf16 conversions (x, qkv_w, proj_w) + rand_matrix transpose
// ---------------------------------------------------------------------------
__global__ __launch_bounds__(256) void prep_kernel(
    const float* __restrict__ x, const float* __restrict__ qw,
    const float* __restrict__ pw, const float* __restrict__ rnd,
    u16* __restrict__ xbf, u16* __restrict__ wbf, u16* __restrict__ pwbf,
    u16* __restrict__ randt) {
  const int NX8 = 3145728, NW8 = 147456, NP8 = 73728, NR = 98304;
  const int total = NX8 + NW8 + NP8 + NR;
  for (int idx = blockIdx.x * 256 + threadIdx.x; idx < total;
       idx += gridDim.x * 256) {
    if (idx < NX8 + NW8 + NP8) {
      const float* src; u16* dst; int k;
      if (idx < NX8) { src = x; dst = xbf; k = idx; }
      else if (idx < NX8 + NW8) { src = qw; dst = wbf; k = idx - NX8; }
      else { src = pw; dst = pwbf; k = idx - NX8 - NW8; }
      float4 a = *(const float4*)(src + (size_t)k * 8);
      float4 b = *(const float4*)(src + (size_t)k * 8 + 4);
      uint4 o;
      o.x = (u32)f2bf(a.x) | ((u32)f2bf(a.y) << 16);
      o.y = (u32)f2bf(a.z) | ((u32)f2bf(a.w) << 16);
      o.z = (u32)f2bf(b.x) | ((u32)f2bf(b.y) << 16);
      o.w = (u32)f2bf(b.z) | ((u32)f2bf(b.w) << 16);
      *(uint4*)(dst + (size_t)k * 8) = o;
    } else {
      int k = idx - NX8 - NW8 - NP8;           // rand_t[h][m][d]
      int h = k >> 13, rem = k & 8191, m = rem >> 6, d = rem & 63;
      randt[k] = f2bf(rnd[(size_t)h * 8192 + d * 128 + m]);
    }
  }
}

// ---------------------------------------------------------------------------
// Fused QKV MFMA GEMM + qf epilogue. BK=64, global_load_lds staging.
// C[i,j] = sum_k xbf[i,k]*wbf[j,k]; bj<6: q -> qf (bf16 [B,H,N,M]);
// bj>=6: v -> vb_t (bf16 [B,H,HD,N]).
// ---------------------------------------------------------------------------
__global__ __launch_bounds__(256) void qkv_qf_kernel(
    const u16* __restrict__ xbf, const u16* __restrict__ wbf,
    const u16* __restrict__ randt, u16* __restrict__ qf,
    u16* __restrict__ vbt) {
  // Als[128*64] | Bls[128*64] (32 KB); epilogue reuses as Qls[2][128][72] (36 KB)
  __shared__ __align__(16) u16 SH[18432];
  u16* Als = SH;
  u16* Bls = SH + 8192;
  const int t = threadIdx.x;
  const int bi = blockIdx.x, bj = blockIdx.y;
  const int w = t >> 6, lane = t & 63, ln = lane & 15, kg = lane >> 4;
  const int wr = w >> 1, wc = w & 1;
  f32x4 acc[4][4];
#pragma unroll
  for (int i = 0; i < 4; ++i)
#pragma unroll
    for (int j = 0; j < 4; ++j) acc[i][j] = fzero();
  const u16* Ag = xbf + (size_t)(bi * 128) * Cc;
  const u16* Bg = wbf + (size_t)(bj * 128) * Cc;
  for (int k0 = 0; k0 < Cc; k0 += 64) {
    stage_gll(Ag + k0, Cc, Als, w, lane);
    stage_gll(Bg + k0, Cc, Bls, w, lane);
    __syncthreads();
#pragma unroll
    for (int ks = 0; ks < 2; ++ks) {
      bf16x8 af[4], bf[4];
#pragma unroll
      for (int i = 0; i < 4; ++i)
        af[i] = *(const bf16x8*)(Als + (wr * 64 + i * 16 + ln) * 64 + ks * 32 +
                                 kg * 8);
#pragma unroll
      for (int j = 0; j < 4; ++j)
        bf[j] = *(const bf16x8*)(Bls + (wc * 64 + j * 16 + ln) * 64 + ks * 32 +
                                 kg * 8);
#pragma unroll
      for (int i = 0; i < 4; ++i)
#pragma unroll
        for (int j = 0; j < 4; ++j) acc[i][j] = mfma16(af[i], bf[j], acc[i][j]);
    }
    __syncthreads();
  }
  const int b = bi >> 3;
  const int ntile = (bi & 7) * 128;
  if (bj >= 6) {
    // ---- V: write transposed bf16 [B,H,64,1024] ----
    const int h = (bj - 6) * 2 + wc;
    u16* vt = vbt + ((size_t)(b * Hc + h) * 64) * 1024;
#pragma unroll
    for (int i = 0; i < 4; ++i)
#pragma unroll
      for (int j = 0; j < 4; ++j) {
        int d = j * 16 + ln;
        int n0 = ntile + wr * 64 + i * 16 + kg * 4;
        uint2 pv;
        pv.x = (u32)f2bf(acc[i][j][0]) | ((u32)f2bf(acc[i][j][1]) << 16);
        pv.y = (u32)f2bf(acc[i][j][2]) | ((u32)f2bf(acc[i][j][3]) << 16);
        *(uint2*)(vt + (size_t)d * 1024 + n0) = pv;
      }
  } else {
    // ---- Q -> qf epilogue ----
#pragma unroll
    for (int i = 0; i < 4; ++i)
#pragma unroll
      for (int j = 0; j < 4; ++j) acc[i][j] *= QSCALE;
    float hn[4][4];
#pragma unroll
    for (int i = 0; i < 4; ++i)
#pragma unroll
      for (int r = 0; r < 4; ++r) {
        float s = acc[i][0][r] * acc[i][0][r] + acc[i][1][r] * acc[i][1][r] +
                  acc[i][2][r] * acc[i][2][r] + acc[i][3][r] * acc[i][3][r];
        s += __shfl_xor(s, 1); s += __shfl_xor(s, 2);
        s += __shfl_xor(s, 4); s += __shfl_xor(s, 8);
        hn[i][r] = 0.5f * s;
      }
    // stage q (bf16) to Qls[head][row][d] (row stride 72)
    u16* Qls = SH;
#pragma unroll
    for (int i = 0; i < 4; ++i)
#pragma unroll
      for (int j = 0; j < 4; ++j)
#pragma unroll
        for (int r = 0; r < 4; ++r)
          Qls[(size_t)(wc * 128 + wr * 64 + i * 16 + kg * 4 + r) * 72 +
              j * 16 + ln] = f2bf(acc[i][j][r]);
    __syncthreads();
    // qf GEMM: wave w -> head (w&1), rows (w>>1)*64..+64, K=64
    const int hq = bj * 2 + (w & 1);
    const int r0q = (w >> 1) * 64;
    const u16* rt = randt + (size_t)hq * Mc * HDc;  // [m][64]
    u16* qfb = qf + ((size_t)(b * Hc + hq) * Nc + ntile) * Mc;
    const u16* qsl = Qls + (size_t)(w & 1) * 128 * 72;
#pragma unroll
    for (int mh = 0; mh < 2; ++mh) {
      f32x4 a2[4][4];
#pragma unroll
      for (int i = 0; i < 4; ++i)
#pragma unroll
        for (int j = 0; j < 4; ++j) a2[i][j] = fzero();
#pragma unroll
      for (int ks = 0; ks < 2; ++ks) {
        bf16x8 af[4], bfr[4];
#pragma unroll
        for (int i = 0; i < 4; ++i)
          af[i] = *(const bf16x8*)(qsl + (size_t)(r0q + i * 16 + ln) * 72 +
                                   ks * 32 + kg * 8);
#pragma unroll
        for (int j = 0; j < 4; ++j)
          bfr[j] = *(const bf16x8*)(rt +
                                    (size_t)(mh * 64 + j * 16 + ln) * 64 +
                                    ks * 32 + kg * 8);
#pragma unroll
        for (int i = 0; i < 4; ++i)
#pragma unroll
          for (int j = 0; j < 4; ++j)
            a2[i][j] = mfma16(af[i], bfr[j], a2[i][j]);
      }
#pragma unroll
      for (int i = 0; i < 4; ++i)
#pragma unroll
        for (int j = 0; j < 4; ++j)
#pragma unroll
          for (int r = 0; r < 4; ++r) {
            int n = r0q + i * 16 + kg * 4 + r;
            float e = expf(a2[i][j][r] - hn[i][r]) * INV_SQRT_M;
            qfb[(size_t)n * Mc + mh * 64 + j * 16 + ln] = f2bf(e);
          }
    }
  }
}

// ---------------------------------------------------------------------------
// kk_inp: per bh, C[128 x 192] = qf^T . [qf | v]  (K = 1024)
// cols 0-127 -> kk (f32), cols 128-191 -> inp (f32). 384 threads, 6 waves.
// ---------------------------------------------------------------------------
__global__ __launch_bounds__(384) void kk_inp_kernel(
    const u16* __restrict__ qf, const u16* __restrict__ vbt,
    float* __restrict__ kk, float* __restrict__ inp) {
  __shared__ u16 Atl[128 * 40];
  __shared__ u16 Vtl[64 * 40];
  const int t = threadIdx.x, bh = blockIdx.x;
  const int w = t >> 6, lane = t & 63, ln = lane & 15, kg = lane >> 4;
  const int wr = w / 3, wc = w % 3;
  const u16* qg = qf + (size_t)bh * Nc * Mc;
  const u16* vg = vbt + (size_t)bh * 64 * 1024;
  f32x4 acc[4][4];
#pragma unroll
  for (int i = 0; i < 4; ++i)
#pragma unroll
    for (int j = 0; j < 4; ++j) acc[i][j] = fzero();
  for (int kt = 0; kt < 32; ++kt) {
    const int n0 = kt * 32;
    if (t < 256) {
      // transpose-stage 32n x 128m of qf into Atl[m][n]
#pragma unroll
      for (int c = 0; c < 2; ++c) {
        int ch = t + c * 256;
        int n = ch >> 4, mc = ch & 15;
        uint4 v = *(const uint4*)(qg + (size_t)(n0 + n) * 128 + mc * 8);
        const u16* pv = (const u16*)&v;
#pragma unroll
        for (int e = 0; e < 8; ++e) Atl[(mc * 8 + e) * 40 + n] = pv[e];
      }
    } else {
      const int tt = t - 256;
#pragma unroll
      for (int c = 0; c < 2; ++c) {
        int ch = tt + c * 128;
        int d = ch >> 2, kc = ch & 3;
        *(uint4*)(Vtl + d * 40 + kc * 8) =
            *(const uint4*)(vg + (size_t)d * 1024 + n0 + kc * 8);
      }
    }
    __syncthreads();
    bf16x8 af[4], bf[4];
#pragma unroll
    for (int i = 0; i < 4; ++i)
      af[i] = *(const bf16x8*)(Atl + (wr * 64 + i * 16 + ln) * 40 + kg * 8);
    if (wc < 2) {
#pragma unroll
      for (int j = 0; j < 4; ++j)
        bf[j] = *(const bf16x8*)(Atl + (wc * 64 + j * 16 + ln) * 40 + kg * 8);
    } else {
#pragma unroll
      for (int j = 0; j < 4; ++j)
        bf[j] = *(const bf16x8*)(Vtl + (j * 16 + ln) * 40 + kg * 8);
    }
#pragma unroll
    for (int i = 0; i < 4; ++i)
#pragma unroll
      for (int j = 0; j < 4; ++j) acc[i][j] = mfma16(af[i], bf[j], acc[i][j]);
    __syncthreads();
  }
  if (wc < 2) {
    float* og = kk + (size_t)bh * Mc * Mc;
#pragma unroll
    for (int i = 0; i < 4; ++i)
#pragma unroll
      for (int j = 0; j < 4; ++j)
#pragma unroll
        for (int r = 0; r < 4; ++r)
          og[(size_t)(wr * 64 + i * 16 + kg * 4 + r) * Mc + wc * 64 + j * 16 +
             ln] = acc[i][j][r];
  } else {
    float* og = inp + (size_t)bh * Mc * HDc;
#pragma unroll
    for (int i = 0; i < 4; ++i)
#pragma unroll
      for (int j = 0; j < 4; ++j)
#pragma unroll
        for (int r = 0; r < 4; ++r)
          og[(size_t)(wr * 64 + i * 16 + kg * 4 + r) * HDc + j * 16 + ln] =
              acc[i][j][r];
  }
}

// ---------------------------------------------------------------------------
// normalize in place + L
// ---------------------------------------------------------------------------
__global__ __launch_bounds__(256) void norm_kernel(float* kk, float* inp,
                                                   float* __restrict__ norms,
                                                   float* __restrict__ Lbuf) {
  __shared__ float nrm[128];
  __shared__ float rowsum[128];
  const int t = threadIdx.x, bh = blockIdx.x;
  float* kkg = kk + (size_t)bh * Mc * Mc;
  float* ig = inp + (size_t)bh * Mc * HDc;
  if (t < 128) {
    float nm = fmaxf(sqrtf(kkg[t * Mc + t]), EPSC);
    nrm[t] = nm;
    norms[(size_t)bh * Mc + t] = nm;
  }
  __syncthreads();
#pragma unroll 8
  for (int e = 0; e < 64; ++e) {
    int idx = e * 256 + t;
    int m = idx >> 7, p = idx & 127;
    kkg[idx] = kkg[idx] / (nrm[m] * nrm[p]);
  }
#pragma unroll 8
  for (int e = 0; e < 32; ++e) {
    int idx = e * 256 + t;
    int m = idx >> 6;
    ig[idx] = ig[idx] / nrm[m];
  }
  __syncthreads();
  if (t < 128) {
    float s = 0.f;
    for (int p = 0; p < 128; ++p) s += fabsf(kkg[t * Mc + p]);
    rowsum[t] = s;
  }
  __syncthreads();
  if (t == 0) {
    float mx = rowsum[0];
    for (int i = 1; i < 128; ++i) mx = fmaxf(mx, rowsum[i]);
    Lbuf[bh] = mx + 1.0f;
  }
}

// ---------------------------------------------------------------------------
// kk = learned_k @ kk @ learned_k, in place
// ---------------------------------------------------------------------------
__global__ __launch_bounds__(256) void kkl_kernel(float* kk,
                                                  const float* __restrict__ lk) {
  __shared__ float Ks[128][132];
  __shared__ float Xs[128][132];
  const int t = threadIdx.x, bh = blockIdx.x;
  float* kg = kk + (size_t)bh * Mc * Mc;
#pragma unroll
  for (int c = 0; c < 16; ++c) {
    int lin = c * 1024 + t * 4;
    int r = lin >> 7, cc = lin & 127;
    float4 a = *(const float4*)(lk + lin);
    Ks[r][cc] = a.x; Ks[r][cc + 1] = a.y; Ks[r][cc + 2] = a.z; Ks[r][cc + 3] = a.w;
    float4 b = *(const float4*)(kg + lin);
    Xs[r][cc] = b.x; Xs[r][cc + 1] = b.y; Xs[r][cc + 2] = b.z; Xs[r][cc + 3] = b.w;
  }
  __syncthreads();
  const int rg = t >> 3, cgp = t & 7;
  const int r0 = rg * 4, c0 = cgp * 16;
  float tmp[4][16] = {};
  for (int p = 0; p < 128; ++p) {
    float kv[4];
#pragma unroll
    for (int i = 0; i < 4; ++i) kv[i] = Ks[r0 + i][p];
    float xv[16];
#pragma unroll
    for (int j = 0; j < 4; ++j)
      *(float4*)&xv[j * 4] = *(const float4*)&Xs[p][c0 + j * 4];
#pragma unroll
    for (int i = 0; i < 4; ++i)
#pragma unroll
      for (int j = 0; j < 16; ++j) tmp[i][j] = fmaf(kv[i], xv[j], tmp[i][j]);
  }
  __syncthreads();
#pragma unroll
  for (int i = 0; i < 4; ++i)
#pragma unroll
    for (int j = 0; j < 4; ++j)
      *(float4*)&Xs[r0 + i][c0 + j * 4] = *(float4*)&tmp[i][j * 4];
  __syncthreads();
  float acc[4][16] = {};
  for (int p = 0; p < 128; ++p) {
    float kv[4];
#pragma unroll
    for (int i = 0; i < 4; ++i) kv[i] = Xs[r0 + i][p];
    float xv[16];
#pragma unroll
    for (int j = 0; j < 4; ++j)
      *(float4*)&xv[j * 4] = *(const float4*)&Ks[p][c0 + j * 4];
#pragma unroll
    for (int i = 0; i < 4; ++i)
#pragma unroll
      for (int j = 0; j < 16; ++j) acc[i][j] = fmaf(kv[i], xv[j], acc[i][j]);
  }
#pragma unroll
  for (int i = 0; i < 4; ++i)
#pragma unroll
    for (int j = 0; j < 4; ++j)
      *(float4*)(kg + (size_t)(r0 + i) * Mc + c0 + j * 4) = *(float4*)&acc[i][j * 4];
}

// ---------------------------------------------------------------------------
// ISTA; epilogue writes xss_t bf16 [B,H,64,128]
// ---------------------------------------------------------------------------
__global__ __launch_bounds__(256) void ista_kernel(
    const float* __restrict__ kkl, const float* __restrict__ inp,
    const float* __restrict__ norms, const float* __restrict__ Lbuf,
    const float* __restrict__ lamp, const float* __restrict__ Lp,
    u16* __restrict__ xsst) {
  __shared__ float kks[128][129];
  __shared__ float xs[128][64];
  const int t = threadIdx.x, bh = blockIdx.x;
  const float* kg = kkl + (size_t)bh * Mc * Mc;
#pragma unroll
  for (int c = 0; c < 16; ++c) {
    int lin = c * 1024 + t * 4;
    int r = lin >> 7, cc = lin & 127;
    float4 a = *(const float4*)(kg + lin);
    kks[r][cc] = a.x; kks[r][cc + 1] = a.y; kks[r][cc + 2] = a.z; kks[r][cc + 3] = a.w;
  }
  const float lam = lamp[0] * 0.1f;
  const float Ll = Lbuf[bh] / Lp[0];
  const float thr = lam / Ll;
  const float invLl = 1.0f / Ll;
  const int mg = t >> 3, dg = t & 7;
  const int m0 = mg * 4, d0 = dg * 8;
  const float* ig = inp + (size_t)bh * Mc * HDc;
  float ri[4][8], xr[4][8];
#pragma unroll
  for (int i = 0; i < 4; ++i) {
    *(float4*)&ri[i][0] = *(const float4*)(ig + (size_t)(m0 + i) * HDc + d0);
    *(float4*)&ri[i][4] = *(const float4*)(ig + (size_t)(m0 + i) * HDc + d0 + 4);
  }
#pragma unroll
  for (int i = 0; i < 4; ++i)
#pragma unroll
    for (int j = 0; j < 8; ++j) xr[i][j] = softf(ri[i][j], lam);
#pragma unroll
  for (int i = 0; i < 4; ++i) {
    *(float4*)&xs[m0 + i][d0] = *(float4*)&xr[i][0];
    *(float4*)&xs[m0 + i][d0 + 4] = *(float4*)&xr[i][4];
  }
  __syncthreads();
  for (int s = 0; s < NUM_STEP_C; ++s) {
    float acc[4][8] = {};
    for (int p = 0; p < 128; ++p) {
      float kv[4];
#pragma unroll
      for (int i = 0; i < 4; ++i) kv[i] = kks[m0 + i][p];
      float xv[8];
      *(float4*)&xv[0] = *(const float4*)&xs[p][d0];
      *(float4*)&xv[4] = *(const float4*)&xs[p][d0 + 4];
#pragma unroll
      for (int i = 0; i < 4; ++i)
#pragma unroll
        for (int j = 0; j < 8; ++j) acc[i][j] = fmaf(kv[i], xv[j], acc[i][j]);
    }
#pragma unroll
    for (int i = 0; i < 4; ++i)
#pragma unroll
      for (int j = 0; j < 8; ++j)
        xr[i][j] = softf(xr[i][j] - (acc[i][j] - ri[i][j]) * invLl, thr);
    __syncthreads();
#pragma unroll
    for (int i = 0; i < 4; ++i) {
      *(float4*)&xs[m0 + i][d0] = *(float4*)&xr[i][0];
      *(float4*)&xs[m0 + i][d0 + 4] = *(float4*)&xr[i][4];
    }
    __syncthreads();
  }
  u16* og = xsst + (size_t)bh * HDc * Mc;
  float invn[4];
#pragma unroll
  for (int i = 0; i < 4; ++i)
    invn[i] = 1.0f / norms[(size_t)bh * Mc + m0 + i];
#pragma unroll
  for (int j = 0; j < 8; ++j) {
    uint2 pv;
    pv.x = (u32)f2bf(xr[0][j] * invn[0]) | ((u32)f2bf(xr[1][j] * invn[1]) << 16);
    pv.y = (u32)f2bf(xr[2][j] * invn[2]) | ((u32)f2bf(xr[3][j] * invn[3]) << 16);
    *(uint2*)(og + (size_t)(d0 + j) * Mc + m0) = pv;
  }
}

// ---------------------------------------------------------------------------
// pvout: attn_bf[b*N+n][h*64+d] = sum_m qf[bh][n][m] * xss_t[bh][d][m]
// ---------------------------------------------------------------------------
__global__ __launch_bounds__(256) void pvout_kernel(
    const u16* __restrict__ qf, const u16* __restrict__ xsst,
    u16* __restrict__ attn) {
  __shared__ u16 Apl[128 * 136];
  __shared__ u16 Bpl[64 * 136];
  const int t = threadIdx.x;
  const int bh = blockIdx.x, nt = blockIdx.y;
  const int b = bh / Hc, h = bh % Hc;
  const int w = t >> 6, lane = t & 63, ln = lane & 15, kg = lane >> 4;
  const u16* qg = qf + ((size_t)bh * Nc + nt * 128) * Mc;
  const u16* xg = xsst + (size_t)bh * HDc * Mc;
#pragma unroll
  for (int c = 0; c < 8; ++c) {
    int ch = t + c * 256;
    int r = ch >> 4, kc = ch & 15;
    *(uint4*)(Apl + r * 136 + kc * 8) =
        *(const uint4*)(qg + (size_t)r * 128 + kc * 8);
  }
#pragma unroll
  for (int c = 0; c < 4; ++c) {
    int ch = t + c * 256;
    int r = ch >> 4, kc = ch & 15;
    *(uint4*)(Bpl + r * 136 + kc * 8) =
        *(const uint4*)(xg + (size_t)r * 128 + kc * 8);
  }
  __syncthreads();
  f32x4 acc[2][4];
#pragma unroll
  for (int i = 0; i < 2; ++i)
#pragma unroll
    for (int j = 0; j < 4; ++j) acc[i][j] = fzero();
#pragma unroll
  for (int ks = 0; ks < 4; ++ks) {
    bf16x8 af[2], bf[4];
#pragma unroll
    for (int i = 0; i < 2; ++i)
      af[i] = *(const bf16x8*)(Apl + (w * 32 + i * 16 + ln) * 136 + ks * 32 +
                               kg * 8);
#pragma unroll
    for (int j = 0; j < 4; ++j)
      bf[j] = *(const bf16x8*)(Bpl + (j * 16 + ln) * 136 + ks * 32 + kg * 8);
#pragma unroll
    for (int i = 0; i < 2; ++i)
#pragma unroll
      for (int j = 0; j < 4; ++j) acc[i][j] = mfma16(af[i], bf[j], acc[i][j]);
  }
#pragma unroll
  for (int i = 0; i < 2; ++i)
#pragma unroll
    for (int j = 0; j < 4; ++j)
#pragma unroll
      for (int r = 0; r < 4; ++r) {
        int n = nt * 128 + w * 32 + i * 16 + kg * 4 + r;
        attn[((size_t)(b * Nc + n)) * Cc + h * 64 + j * 16 + ln] =
            f2bf(acc[i][j][r]);
      }
}

// ---------------------------------------------------------------------------
// proj: out[i][j] = sum_k attn_bf[i][k] * pwbf[j][k] + bias[j]  (f32 out)
// BK=64, global_load_lds staging.
// ---------------------------------------------------------------------------
__global__ __launch_bounds__(256) void proj_kernel(
    const u16* __restrict__ abf, const u16* __restrict__ pwbf,
    const float* __restrict__ bias, float* __restrict__ out) {
  __shared__ __align__(16) u16 Als[128 * 64];
  __shared__ __align__(16) u16 Bls[128 * 64];
  const int t = threadIdx.x;
  const int bi = blockIdx.x, bj = blockIdx.y;
  const int w = t >> 6, lane = t & 63, ln = lane & 15, kg = lane >> 4;
  const int wr = w >> 1, wc = w & 1;
  f32x4 acc[4][4];
#pragma unroll
  for (int i = 0; i < 4; ++i)
#pragma unroll
    for (int j = 0; j < 4; ++j) acc[i][j] = fzero();
  const u16* Ag = abf + (size_t)(bi * 128) * Cc;
  const u16* Bg = pwbf + (size_t)(bj * 128) * Cc;
  for (int k0 = 0; k0 < Cc; k0 += 64) {
    stage_gll(Ag + k0, Cc, Als, w, lane);
    stage_gll(Bg + k0, Cc, Bls, w, lane);
    __syncthreads();
#pragma unroll
    for (int ks = 0; ks < 2; ++ks) {
      bf16x8 af[4], bf[4];
#pragma unroll
      for (int i = 0; i < 4; ++i)
        af[i] = *(const bf16x8*)(Als + (wr * 64 + i * 16 + ln) * 64 + ks * 32 +
                                 kg * 8);
#pragma unroll
      for (int j = 0; j < 4; ++j)
        bf[j] = *(const bf16x8*)(Bls + (wc * 64 + j * 16 + ln) * 64 + ks * 32 +
                                 kg * 8);
#pragma unroll
      for (int i = 0; i < 4; ++i)
#pragma unroll
        for (int j = 0; j < 4; ++j) acc[i][j] = mfma16(af[i], bf[j], acc[i][j]);
    }
    __syncthreads();
  }
#pragma unroll
  for (int j = 0; j < 4; ++j) {
    const int gc = bj * 128 + wc * 64 + j * 16 + ln;
    const float bv = bias[gc];
#pragma unroll
    for (int i = 0; i < 4; ++i) {
      const int gr = bi * 128 + wr * 64 + i * 16 + kg * 4;
#pragma unroll
      for (int r = 0; r < 4; ++r)
        out[(size_t)(gr + r) * Cc + gc] = acc[i][j][r] + bv;
    }
  }
}

// ---------------------------------------------------------------------------
extern "C" void kernel_launch(void* const* d_in, const int* in_sizes, int n_in,
                              void* d_out, int out_size, void* d_ws,
                              size_t ws_size, hipStream_t stream) {
  const float* x = (const float*)d_in[0];
  const float* qkv_w = (const float*)d_in[1];
  const float* proj_w = (const float*)d_in[2];
  const float* proj_b = (const float*)d_in[3];
  const float* rand_matrix = (const float*)d_in[4];
  const float* learned_k = (const float*)d_in[5];
  const float* learned_lam = (const float*)d_in[6];
  const float* learned_L = (const float*)d_in[7];
  float* out = (float*)d_out;

  const size_t SX = 25165824;   // x_bf / attn_bf (aliased)
  const size_t SQF = 50331648;  // qf
  const size_t SVT = 25165824;  // vb_t
  const size_t SXT = 3145728;   // xss_t
  const size_t SW = 1179648;    // w_bf
  const size_t SPW = 589824;    // pw_bf
  const size_t SRT = 98304;     // rand_t
  const size_t U16TOT = SX + SQF + SVT + SXT + SW + SPW + SRT;
  const size_t SKK = 6291456, SIN = 3145728, SNM = 49152, SLB = 384;
  const size_t need = U16TOT * 2 + (SKK + SIN + SNM + SLB) * 4;
  if (ws_size < need) return;  // graceful fail rather than OOB crash

  u16* xbf = (u16*)d_ws;
  u16* qfb = xbf + SX;
  u16* vbt = qfb + SQF;
  u16* xsst = vbt + SVT;
  u16* wbf = xsst + SXT;
  u16* pwbf = wbf + SW;
  u16* randt = pwbf + SPW;
  float* kkf = (float*)(randt + SRT);
  float* inpf = kkf + SKK;
  float* normsf = inpf + SIN;
  float* Lb = normsf + SNM;
  u16* attnbf = xbf;  // alias: x_bf dead after qkv

  prep_kernel<<<2048, 256, 0, stream>>>(x, qkv_w, proj_w, rand_matrix, xbf,
                                        wbf, pwbf, randt);
  qkv_qf_kernel<<<dim3(256, 12), 256, 0, stream>>>(xbf, wbf, randt, qfb, vbt);
  kk_inp_kernel<<<Bc * Hc, 384, 0, stream>>>(qfb, vbt, kkf, inpf);
  norm_kernel<<<Bc * Hc, 256, 0, stream>>>(kkf, inpf, normsf, Lb);
  kkl_kernel<<<Bc * Hc, 256, 0, stream>>>(kkf, learned_k);
  ista_kernel<<<Bc * Hc, 256, 0, stream>>>(kkf, inpf, normsf, Lb, learned_lam,
                                           learned_L, xsst);
  pvout_kernel<<<dim3(Bc * Hc, Nc / 128), 256, 0, stream>>>(qfb, xsst, attnbf);
  proj_kernel<<<dim3(256, 6), 256, 0, stream>>>(attnbf, pwbf, proj_b, out);
}

// Round 5
// 736.516 us; speedup vs baseline: 1.0803x; 1.0803x over previous
//
#include <hip/hip_runtime.h>
#include <math.h>

typedef unsigned short u16;
typedef unsigned int u32;
typedef __attribute__((ext_vector_type(8))) short bf16x8;
typedef __attribute__((ext_vector_type(4))) float f32x4;

constexpr int Bc = 32, Nc = 1024, Cc = 768, Hc = 12, HDc = 64, Mc = 128;
constexpr int NUM_STEP_C = 8;
constexpr float QSCALE = 0.35355339059327376f;      // 8^-0.5
constexpr float INV_SQRT_M = 0.088388347648318447f; // 1/sqrt(128)
constexpr float EPSC = 1e-12f;

__device__ __forceinline__ float softf(float z, float thr) {
  float az = fabsf(z) - thr;
  float g = 0.5f * az * (1.0f + erff(az * 0.70710678118654752f));
  return (z > 0.f) ? g : ((z < 0.f) ? -g : 0.f);
}

__device__ __forceinline__ u16 f2bf(float f) {
  u32 u = __float_as_uint(f);
  u += 0x7fffu + ((u >> 16) & 1u);
  return (u16)(u >> 16);
}

__device__ __forceinline__ f32x4 fzero() {
  f32x4 z; z[0] = 0.f; z[1] = 0.f; z[2] = 0.f; z[3] = 0.f; return z;
}

__device__ __forceinline__ f32x4 mfma16(bf16x8 a, bf16x8 b, f32x4 c) {
  return __builtin_amdgcn_mfma_f32_16x16x32_bf16(a, b, c, 0, 0, 0);
}

// Swizzled read offset within a [*][64]-u16 LDS tile: col(u16) XOR'ed by row
#define SWZ_COL(col, row) ((col) ^ (((row) & 7) << 3))

// Stage 32 rows x 64 u16 of a row-major (ld elems) global tile into linear
// LDS [.][64] with the inverse swizzle pre-applied to the GLOBAL source, so
// LDS[r][c] = G[r][c ^ ((r&7)<<3)].  (rule #21: linear dest via
// global_load_lds, swizzle on source + on read.)
__device__ __forceinline__ void stage_swz(const u16* __restrict__ g, int ld,
                                          u16* lds, int w, int lane) {
  const int rr = lane >> 3;                 // 0..7 row within 8-row call
  const int cs = ((lane & 7) ^ rr) << 3;    // pre-swizzled col (u16)
#pragma unroll
  for (int c = 0; c < 4; ++c) {
    const int r0 = w * 32 + c * 8;
    __builtin_amdgcn_global_load_lds(
        (const __attribute__((address_space(1))) void*)(g + (size_t)(r0 + rr) * ld + cs),
        (__attribute__((address_space(3))) void*)(lds + r0 * 64), 16, 0, 0);
  }
}

// ---------------------------------------------------------------------------
// prep: f32 -> bf16 conversions (x, qkv_w, proj_w) + rand_matrix transpose
// ---------------------------------------------------------------------------
__global__ __launch_bounds__(256) void prep_kernel(
    const float* __restrict__ x, const float* __restrict__ qw,
    const float* __restrict__ pw, const float* __restrict__ rnd,
    u16* __restrict__ xbf, u16* __restrict__ wbf, u16* __restrict__ pwbf,
    u16* __restrict__ randt) {
  const int NX8 = 3145728, NW8 = 147456, NP8 = 73728, NR = 98304;
  const int total = NX8 + NW8 + NP8 + NR;
  for (int idx = blockIdx.x * 256 + threadIdx.x; idx < total;
       idx += gridDim.x * 256) {
    if (idx < NX8 + NW8 + NP8) {
      const float* src; u16* dst; int k;
      if (idx < NX8) { src = x; dst = xbf; k = idx; }
      else if (idx < NX8 + NW8) { src = qw; dst = wbf; k = idx - NX8; }
      else { src = pw; dst = pwbf; k = idx - NX8 - NW8; }
      float4 a = *(const float4*)(src + (size_t)k * 8);
      float4 b = *(const float4*)(src + (size_t)k * 8 + 4);
      uint4 o;
      o.x = (u32)f2bf(a.x) | ((u32)f2bf(a.y) << 16);
      o.y = (u32)f2bf(a.z) | ((u32)f2bf(a.w) << 16);
      o.z = (u32)f2bf(b.x) | ((u32)f2bf(b.y) << 16);
      o.w = (u32)f2bf(b.z) | ((u32)f2bf(b.w) << 16);
      *(uint4*)(dst + (size_t)k * 8) = o;
    } else {
      int k = idx - NX8 - NW8 - NP8;           // rand_t[h][m][d]
      int h = k >> 13, rem = k & 8191, m = rem >> 6, d = rem & 63;
      randt[k] = f2bf(rnd[(size_t)h * 8192 + d * 128 + m]);
    }
  }
}

// ---------------------------------------------------------------------------
// Fused QKV MFMA GEMM + qf epilogue. BK=64, swizzled global_load_lds staging.
// bj<6: q -> qf_t (bf16 [B,H,M,N]); bj>=6: v -> vb_t (bf16 [B,H,HD,N]).
// ---------------------------------------------------------------------------
__global__ __launch_bounds__(256) void qkv_qf_kernel(
    const u16* __restrict__ xbf, const u16* __restrict__ wbf,
    const u16* __restrict__ randt, u16* __restrict__ qft,
    u16* __restrict__ vbt) {
  // Als[128*64] | Bls[128*64] (32 KB); epilogue reuses as Qls[2][128][72]
  __shared__ __align__(16) u16 SH[18432];
  u16* Als = SH;
  u16* Bls = SH + 8192;
  const int t = threadIdx.x;
  const int bi = blockIdx.x, bj = blockIdx.y;
  const int w = t >> 6, lane = t & 63, ln = lane & 15, kg = lane >> 4;
  const int wr = w >> 1, wc = w & 1;
  f32x4 acc[4][4];
#pragma unroll
  for (int i = 0; i < 4; ++i)
#pragma unroll
    for (int j = 0; j < 4; ++j) acc[i][j] = fzero();
  const u16* Ag = xbf + (size_t)(bi * 128) * Cc;
  const u16* Bg = wbf + (size_t)(bj * 128) * Cc;
  for (int k0 = 0; k0 < Cc; k0 += 64) {
    stage_swz(Ag + k0, Cc, Als, w, lane);
    stage_swz(Bg + k0, Cc, Bls, w, lane);
    __syncthreads();
#pragma unroll
    for (int ks = 0; ks < 2; ++ks) {
      const int cb = ks * 32 + kg * 8;
      bf16x8 af[4], bf[4];
#pragma unroll
      for (int i = 0; i < 4; ++i)
        af[i] = *(const bf16x8*)(Als + (wr * 64 + i * 16 + ln) * 64 +
                                 SWZ_COL(cb, ln));
#pragma unroll
      for (int j = 0; j < 4; ++j)
        bf[j] = *(const bf16x8*)(Bls + (wc * 64 + j * 16 + ln) * 64 +
                                 SWZ_COL(cb, ln));
#pragma unroll
      for (int i = 0; i < 4; ++i)
#pragma unroll
        for (int j = 0; j < 4; ++j) acc[i][j] = mfma16(af[i], bf[j], acc[i][j]);
    }
    __syncthreads();
  }
  const int b = bi >> 3;
  const int ntile = (bi & 7) * 128;
  if (bj >= 6) {
    // ---- V: write transposed bf16 [B,H,64,1024] ----
    const int h = (bj - 6) * 2 + wc;
    u16* vt = vbt + ((size_t)(b * Hc + h) * 64) * 1024;
#pragma unroll
    for (int i = 0; i < 4; ++i)
#pragma unroll
      for (int j = 0; j < 4; ++j) {
        int d = j * 16 + ln;
        int n0 = ntile + wr * 64 + i * 16 + kg * 4;
        uint2 pv;
        pv.x = (u32)f2bf(acc[i][j][0]) | ((u32)f2bf(acc[i][j][1]) << 16);
        pv.y = (u32)f2bf(acc[i][j][2]) | ((u32)f2bf(acc[i][j][3]) << 16);
        *(uint2*)(vt + (size_t)d * 1024 + n0) = pv;
      }
  } else {
    // ---- Q -> qf_t epilogue ----
#pragma unroll
    for (int i = 0; i < 4; ++i)
#pragma unroll
      for (int j = 0; j < 4; ++j) acc[i][j] *= QSCALE;
    float hn[4][4];
#pragma unroll
    for (int i = 0; i < 4; ++i)
#pragma unroll
      for (int r = 0; r < 4; ++r) {
        float s = acc[i][0][r] * acc[i][0][r] + acc[i][1][r] * acc[i][1][r] +
                  acc[i][2][r] * acc[i][2][r] + acc[i][3][r] * acc[i][3][r];
        s += __shfl_xor(s, 1); s += __shfl_xor(s, 2);
        s += __shfl_xor(s, 4); s += __shfl_xor(s, 8);
        hn[i][r] = 0.5f * s;
      }
    // stage q (bf16) to Qls[head][row][d] (row stride 72)
    u16* Qls = SH;
#pragma unroll
    for (int i = 0; i < 4; ++i)
#pragma unroll
      for (int j = 0; j < 4; ++j)
#pragma unroll
        for (int r = 0; r < 4; ++r)
          Qls[(size_t)(wc * 128 + wr * 64 + i * 16 + kg * 4 + r) * 72 +
              j * 16 + ln] = f2bf(acc[i][j][r]);
    __syncthreads();
    // qf GEMM: wave w -> head (w&1), rows (w>>1)*64..+64, K=64
    const int hq = bj * 2 + (w & 1);
    const int r0q = (w >> 1) * 64;
    const u16* rt = randt + (size_t)hq * Mc * HDc;  // [m][64]
    u16* qtb = qft + ((size_t)(b * Hc + hq) * Mc) * Nc;  // [m][n]
    const u16* qsl = Qls + (size_t)(w & 1) * 128 * 72;
#pragma unroll
    for (int mh = 0; mh < 2; ++mh) {
      f32x4 a2[4][4];
#pragma unroll
      for (int i = 0; i < 4; ++i)
#pragma unroll
        for (int j = 0; j < 4; ++j) a2[i][j] = fzero();
#pragma unroll
      for (int ks = 0; ks < 2; ++ks) {
        bf16x8 af[4], bfr[4];
#pragma unroll
        for (int i = 0; i < 4; ++i)
          af[i] = *(const bf16x8*)(qsl + (size_t)(r0q + i * 16 + ln) * 72 +
                                   ks * 32 + kg * 8);
#pragma unroll
        for (int j = 0; j < 4; ++j)
          bfr[j] = *(const bf16x8*)(rt +
                                    (size_t)(mh * 64 + j * 16 + ln) * 64 +
                                    ks * 32 + kg * 8);
#pragma unroll
        for (int i = 0; i < 4; ++i)
#pragma unroll
          for (int j = 0; j < 4; ++j)
            a2[i][j] = mfma16(af[i], bfr[j], a2[i][j]);
      }
      // qf_t[m][n] stores: uint2 = 4 consecutive n per (i,j)
#pragma unroll
      for (int i = 0; i < 4; ++i)
#pragma unroll
        for (int j = 0; j < 4; ++j) {
          const int m = mh * 64 + j * 16 + ln;
          const int n0 = ntile + r0q + i * 16 + kg * 4;
          float e0 = expf(a2[i][j][0] - hn[i][0]) * INV_SQRT_M;
          float e1 = expf(a2[i][j][1] - hn[i][1]) * INV_SQRT_M;
          float e2 = expf(a2[i][j][2] - hn[i][2]) * INV_SQRT_M;
          float e3 = expf(a2[i][j][3] - hn[i][3]) * INV_SQRT_M;
          uint2 pv;
          pv.x = (u32)f2bf(e0) | ((u32)f2bf(e1) << 16);
          pv.y = (u32)f2bf(e2) | ((u32)f2bf(e3) << 16);
          *(uint2*)(qtb + (size_t)m * Nc + n0) = pv;
        }
    }
  }
}

// ---------------------------------------------------------------------------
// kk_inp: per bh, C[128 x 192] = qf_t . [qf_t | vbt]^T over n (K = 1024).
// All operands n-contiguous -> pure NT GEMM, swizzled gll staging, no
// transposes. cols 0-127 -> kk (f32), cols 128-191 -> inp. 384 thr, 6 waves.
// ---------------------------------------------------------------------------
__global__ __launch_bounds__(384) void kk_inp_kernel(
    const u16* __restrict__ qft, const u16* __restrict__ vbt,
    float* __restrict__ kk, float* __restrict__ inp) {
  __shared__ __align__(16) u16 Atl[128 * 64];
  __shared__ __align__(16) u16 Vtl[64 * 64];
  const int t = threadIdx.x, bh = blockIdx.x;
  const int w = t >> 6, lane = t & 63, ln = lane & 15, kg = lane >> 4;
  const int wr = w / 3, wc = w % 3;
  const u16* qg = qft + (size_t)bh * Mc * Nc;   // [m][n]
  const u16* vg = vbt + (size_t)bh * 64 * Nc;   // [d][n]
  const int rr = lane >> 3;
  const int cs = ((lane & 7) ^ rr) << 3;
  f32x4 acc[4][4];
#pragma unroll
  for (int i = 0; i < 4; ++i)
#pragma unroll
    for (int j = 0; j < 4; ++j) acc[i][j] = fzero();
  for (int kt = 0; kt < 16; ++kt) {
    const int n0 = kt * 64;
    __syncthreads();  // previous reads done before overwrite
#pragma unroll
    for (int q = 0; q < 4; ++q) {
      const int idx = w * 4 + q;   // 0..23: 16 qf_t calls + 8 vbt calls
      if (idx < 16) {
        __builtin_amdgcn_global_load_lds(
            (const __attribute__((address_space(1))) void*)(
                qg + (size_t)(idx * 8 + rr) * Nc + n0 + cs),
            (__attribute__((address_space(3))) void*)(Atl + idx * 8 * 64), 16,
            0, 0);
      } else {
        __builtin_amdgcn_global_load_lds(
            (const __attribute__((address_space(1))) void*)(
                vg + (size_t)((idx - 16) * 8 + rr) * Nc + n0 + cs),
            (__attribute__((address_space(3))) void*)(Vtl + (idx - 16) * 8 * 64),
            16, 0, 0);
      }
    }
    __syncthreads();
#pragma unroll
    for (int ks = 0; ks < 2; ++ks) {
      const int cb = ks * 32 + kg * 8;
      bf16x8 af[4], bf[4];
#pragma unroll
      for (int i = 0; i < 4; ++i)
        af[i] = *(const bf16x8*)(Atl + (wr * 64 + i * 16 + ln) * 64 +
                                 SWZ_COL(cb, ln));
      if (wc < 2) {
#pragma unroll
        for (int j = 0; j < 4; ++j)
          bf[j] = *(const bf16x8*)(Atl + (wc * 64 + j * 16 + ln) * 64 +
                                   SWZ_COL(cb, ln));
      } else {
#pragma unroll
        for (int j = 0; j < 4; ++j)
          bf[j] = *(const bf16x8*)(Vtl + (j * 16 + ln) * 64 + SWZ_COL(cb, ln));
      }
#pragma unroll
      for (int i = 0; i < 4; ++i)
#pragma unroll
        for (int j = 0; j < 4; ++j) acc[i][j] = mfma16(af[i], bf[j], acc[i][j]);
    }
  }
  if (wc < 2) {
    float* og = kk + (size_t)bh * Mc * Mc;
#pragma unroll
    for (int i = 0; i < 4; ++i)
#pragma unroll
      for (int j = 0; j < 4; ++j)
#pragma unroll
        for (int r = 0; r < 4; ++r)
          og[(size_t)(wr * 64 + i * 16 + kg * 4 + r) * Mc + wc * 64 + j * 16 +
             ln] = acc[i][j][r];
  } else {
    float* og = inp + (size_t)bh * Mc * HDc;
#pragma unroll
    for (int i = 0; i < 4; ++i)
#pragma unroll
      for (int j = 0; j < 4; ++j)
#pragma unroll
        for (int r = 0; r < 4; ++r)
          og[(size_t)(wr * 64 + i * 16 + kg * 4 + r) * HDc + j * 16 + ln] =
              acc[i][j][r];
  }
}

// ---------------------------------------------------------------------------
// normalize in place + L
// ---------------------------------------------------------------------------
__global__ __launch_bounds__(256) void norm_kernel(float* kk, float* inp,
                                                   float* __restrict__ norms,
                                                   float* __restrict__ Lbuf) {
  __shared__ float nrm[128];
  __shared__ float rowsum[128];
  const int t = threadIdx.x, bh = blockIdx.x;
  float* kkg = kk + (size_t)bh * Mc * Mc;
  float* ig = inp + (size_t)bh * Mc * HDc;
  if (t < 128) {
    float nm = fmaxf(sqrtf(kkg[t * Mc + t]), EPSC);
    nrm[t] = nm;
    norms[(size_t)bh * Mc + t] = nm;
  }
  __syncthreads();
#pragma unroll 8
  for (int e = 0; e < 64; ++e) {
    int idx = e * 256 + t;
    int m = idx >> 7, p = idx & 127;
    kkg[idx] = kkg[idx] / (nrm[m] * nrm[p]);
  }
#pragma unroll 8
  for (int e = 0; e < 32; ++e) {
    int idx = e * 256 + t;
    int m = idx >> 6;
    ig[idx] = ig[idx] / nrm[m];
  }
  __syncthreads();
  if (t < 128) {
    float s = 0.f;
    for (int p = 0; p < 128; ++p) s += fabsf(kkg[t * Mc + p]);
    rowsum[t] = s;
  }
  __syncthreads();
  if (t == 0) {
    float mx = rowsum[0];
    for (int i = 1; i < 128; ++i) mx = fmaxf(mx, rowsum[i]);
    Lbuf[bh] = mx + 1.0f;
  }
}

// ---------------------------------------------------------------------------
// kk = learned_k @ kk @ learned_k, in place
// ---------------------------------------------------------------------------
__global__ __launch_bounds__(256) void kkl_kernel(float* kk,
                                                  const float* __restrict__ lk) {
  __shared__ float Ks[128][132];
  __shared__ float Xs[128][132];
  const int t = threadIdx.x, bh = blockIdx.x;
  float* kg = kk + (size_t)bh * Mc * Mc;
#pragma unroll
  for (int c = 0; c < 16; ++c) {
    int lin = c * 1024 + t * 4;
    int r = lin >> 7, cc = lin & 127;
    float4 a = *(const float4*)(lk + lin);
    Ks[r][cc] = a.x; Ks[r][cc + 1] = a.y; Ks[r][cc + 2] = a.z; Ks[r][cc + 3] = a.w;
    float4 b = *(const float4*)(kg + lin);
    Xs[r][cc] = b.x; Xs[r][cc + 1] = b.y; Xs[r][cc + 2] = b.z; Xs[r][cc + 3] = b.w;
  }
  __syncthreads();
  const int rg = t >> 3, cgp = t & 7;
  const int r0 = rg * 4, c0 = cgp * 16;
  float tmp[4][16] = {};
  for (int p = 0; p < 128; ++p) {
    float kv[4];
#pragma unroll
    for (int i = 0; i < 4; ++i) kv[i] = Ks[r0 + i][p];
    float xv[16];
#pragma unroll
    for (int j = 0; j < 4; ++j)
      *(float4*)&xv[j * 4] = *(const float4*)&Xs[p][c0 + j * 4];
#pragma unroll
    for (int i = 0; i < 4; ++i)
#pragma unroll
      for (int j = 0; j < 16; ++j) tmp[i][j] = fmaf(kv[i], xv[j], tmp[i][j]);
  }
  __syncthreads();
#pragma unroll
  for (int i = 0; i < 4; ++i)
#pragma unroll
    for (int j = 0; j < 4; ++j)
      *(float4*)&Xs[r0 + i][c0 + j * 4] = *(float4*)&tmp[i][j * 4];
  __syncthreads();
  float acc[4][16] = {};
  for (int p = 0; p < 128; ++p) {
    float kv[4];
#pragma unroll
    for (int i = 0; i < 4; ++i) kv[i] = Xs[r0 + i][p];
    float xv[16];
#pragma unroll
    for (int j = 0; j < 4; ++j)
      *(float4*)&xv[j * 4] = *(const float4*)&Ks[p][c0 + j * 4];
#pragma unroll
    for (int i = 0; i < 4; ++i)
#pragma unroll
      for (int j = 0; j < 16; ++j) acc[i][j] = fmaf(kv[i], xv[j], acc[i][j]);
  }
#pragma unroll
  for (int i = 0; i < 4; ++i)
#pragma unroll
    for (int j = 0; j < 4; ++j)
      *(float4*)(kg + (size_t)(r0 + i) * Mc + c0 + j * 4) = *(float4*)&acc[i][j * 4];
}

// ---------------------------------------------------------------------------
// ISTA; epilogue writes xss_t bf16 [B,H,64,128]
// ---------------------------------------------------------------------------
__global__ __launch_bounds__(256) void ista_kernel(
    const float* __restrict__ kkl, const float* __restrict__ inp,
    const float* __restrict__ norms, const float* __restrict__ Lbuf,
    const float* __restrict__ lamp, const float* __restrict__ Lp,
    u16* __restrict__ xsst) {
  __shared__ float kks[128][129];
  __shared__ float xs[128][64];
  const int t = threadIdx.x, bh = blockIdx.x;
  const float* kg = kkl + (size_t)bh * Mc * Mc;
#pragma unroll
  for (int c = 0; c < 16; ++c) {
    int lin = c * 1024 + t * 4;
    int r = lin >> 7, cc = lin & 127;
    float4 a = *(const float4*)(kg + lin);
    kks[r][cc] = a.x; kks[r][cc + 1] = a.y; kks[r][cc + 2] = a.z; kks[r][cc + 3] = a.w;
  }
  const float lam = lamp[0] * 0.1f;
  const float Ll = Lbuf[bh] / Lp[0];
  const float thr = lam / Ll;
  const float invLl = 1.0f / Ll;
  const int mg = t >> 3, dg = t & 7;
  const int m0 = mg * 4, d0 = dg * 8;
  const float* ig = inp + (size_t)bh * Mc * HDc;
  float ri[4][8], xr[4][8];
#pragma unroll
  for (int i = 0; i < 4; ++i) {
    *(float4*)&ri[i][0] = *(const float4*)(ig + (size_t)(m0 + i) * HDc + d0);
    *(float4*)&ri[i][4] = *(const float4*)(ig + (size_t)(m0 + i) * HDc + d0 + 4);
  }
#pragma unroll
  for (int i = 0; i < 4; ++i)
#pragma unroll
    for (int j = 0; j < 8; ++j) xr[i][j] = softf(ri[i][j], lam);
#pragma unroll
  for (int i = 0; i < 4; ++i) {
    *(float4*)&xs[m0 + i][d0] = *(float4*)&xr[i][0];
    *(float4*)&xs[m0 + i][d0 + 4] = *(float4*)&xr[i][4];
  }
  __syncthreads();
  for (int s = 0; s < NUM_STEP_C; ++s) {
    float acc[4][8] = {};
    for (int p = 0; p < 128; ++p) {
      float kv[4];
#pragma unroll
      for (int i = 0; i < 4; ++i) kv[i] = kks[m0 + i][p];
      float xv[8];
      *(float4*)&xv[0] = *(const float4*)&xs[p][d0];
      *(float4*)&xv[4] = *(const float4*)&xs[p][d0 + 4];
#pragma unroll
      for (int i = 0; i < 4; ++i)
#pragma unroll
        for (int j = 0; j < 8; ++j) acc[i][j] = fmaf(kv[i], xv[j], acc[i][j]);
    }
#pragma unroll
    for (int i = 0; i < 4; ++i)
#pragma unroll
      for (int j = 0; j < 8; ++j)
        xr[i][j] = softf(xr[i][j] - (acc[i][j] - ri[i][j]) * invLl, thr);
    __syncthreads();
#pragma unroll
    for (int i = 0; i < 4; ++i) {
      *(float4*)&xs[m0 + i][d0] = *(float4*)&xr[i][0];
      *(float4*)&xs[m0 + i][d0 + 4] = *(float4*)&xr[i][4];
    }
    __syncthreads();
  }
  u16* og = xsst + (size_t)bh * HDc * Mc;
  float invn[4];
#pragma unroll
  for (int i = 0; i < 4; ++i)
    invn[i] = 1.0f / norms[(size_t)bh * Mc + m0 + i];
#pragma unroll
  for (int j = 0; j < 8; ++j) {
    uint2 pv;
    pv.x = (u32)f2bf(xr[0][j] * invn[0]) | ((u32)f2bf(xr[1][j] * invn[1]) << 16);
    pv.y = (u32)f2bf(xr[2][j] * invn[2]) | ((u32)f2bf(xr[3][j] * invn[3]) << 16);
    *(uint2*)(og + (size_t)(d0 + j) * Mc + m0) = pv;
  }
}

// ---------------------------------------------------------------------------
// pvout: attn_bf[b*N+n][h*64+d] = sum_m qf_t[bh][m][n] * xss_t[bh][d][m]
// Global-direct TN: A-frag via 8 scalar u16 loads (L2), B-frag contiguous.
// No LDS, no barriers. grid (384, 8), 256 thr, 4 waves x 32 n-rows.
// ---------------------------------------------------------------------------
__global__ __launch_bounds__(256) void pvout_kernel(
    const u16* __restrict__ qft, const u16* __restrict__ xsst,
    u16* __restrict__ attn) {
  const int t = threadIdx.x;
  const int bh = blockIdx.x, nt = blockIdx.y;
  const int b = bh / Hc, h = bh % Hc;
  const int w = t >> 6, lane = t & 63, ln = lane & 15, kg = lane >> 4;
  const u16* qt = qft + (size_t)bh * Mc * Nc;   // [m][n]
  const u16* xg = xsst + (size_t)bh * HDc * Mc; // [d][m]
  f32x4 acc[2][4];
#pragma unroll
  for (int i = 0; i < 2; ++i)
#pragma unroll
    for (int j = 0; j < 4; ++j) acc[i][j] = fzero();
#pragma unroll
  for (int ks = 0; ks < 4; ++ks) {
    const int m8 = ks * 32 + kg * 8;
    bf16x8 af[2];
#pragma unroll
    for (int i = 0; i < 2; ++i) {
      const int n = nt * 128 + w * 32 + i * 16 + ln;
      const u16* p = qt + (size_t)m8 * Nc + n;
#pragma unroll
      for (int e = 0; e < 8; ++e) af[i][e] = (short)p[(size_t)e * Nc];
    }
    bf16x8 bf[4];
#pragma unroll
    for (int j = 0; j < 4; ++j)
      bf[j] = *(const bf16x8*)(xg + (size_t)(j * 16 + ln) * Mc + m8);
#pragma unroll
    for (int i = 0; i < 2; ++i)
#pragma unroll
      for (int j = 0; j < 4; ++j) acc[i][j] = mfma16(af[i], bf[j], acc[i][j]);
  }
#pragma unroll
  for (int i = 0; i < 2; ++i)
#pragma unroll
    for (int j = 0; j < 4; ++j)
#pragma unroll
      for (int r = 0; r < 4; ++r) {
        int n = nt * 128 + w * 32 + i * 16 + kg * 4 + r;
        attn[((size_t)(b * Nc + n)) * Cc + h * 64 + j * 16 + ln] =
            f2bf(acc[i][j][r]);
      }
}

// ---------------------------------------------------------------------------
// proj: out[i][j] = sum_k attn_bf[i][k] * pwbf[j][k] + bias[j]  (f32 out)
// BK=64, swizzled global_load_lds staging.
// ---------------------------------------------------------------------------
__global__ __launch_bounds__(256) void proj_kernel(
    const u16* __restrict__ abf, const u16* __restrict__ pwbf,
    const float* __restrict__ bias, float* __restrict__ out) {
  __shared__ __align__(16) u16 Als[128 * 64];
  __shared__ __align__(16) u16 Bls[128 * 64];
  const int t = threadIdx.x;
  const int bi = blockIdx.x, bj = blockIdx.y;
  const int w = t >> 6, lane = t & 63, ln = lane & 15, kg = lane >> 4;
  const int wr = w >> 1, wc = w & 1;
  f32x4 acc[4][4];
#pragma unroll
  for (int i = 0; i < 4; ++i)
#pragma unroll
    for (int j = 0; j < 4; ++j) acc[i][j] = fzero();
  const u16* Ag = abf + (size_t)(bi * 128) * Cc;
  const u16* Bg = pwbf + (size_t)(bj * 128) * Cc;
  for (int k0 = 0; k0 < Cc; k0 += 64) {
    stage_swz(Ag + k0, Cc, Als, w, lane);
    stage_swz(Bg + k0, Cc, Bls, w, lane);
    __syncthreads();
#pragma unroll
    for (int ks = 0; ks < 2; ++ks) {
      const int cb = ks * 32 + kg * 8;
      bf16x8 af[4], bf[4];
#pragma unroll
      for (int i = 0; i < 4; ++i)
        af[i] = *(const bf16x8*)(Als + (wr * 64 + i * 16 + ln) * 64 +
                                 SWZ_COL(cb, ln));
#pragma unroll
      for (int j = 0; j < 4; ++j)
        bf[j] = *(const bf16x8*)(Bls + (wc * 64 + j * 16 + ln) * 64 +
                                 SWZ_COL(cb, ln));
#pragma unroll
      for (int i = 0; i < 4; ++i)
#pragma unroll
        for (int j = 0; j < 4; ++j) acc[i][j] = mfma16(af[i], bf[j], acc[i][j]);
    }
    __syncthreads();
  }
#pragma unroll
  for (int j = 0; j < 4; ++j) {
    const int gc = bj * 128 + wc * 64 + j * 16 + ln;
    const float bv = bias[gc];
#pragma unroll
    for (int i = 0; i < 4; ++i) {
      const int gr = bi * 128 + wr * 64 + i * 16 + kg * 4;
#pragma unroll
      for (int r = 0; r < 4; ++r)
        out[(size_t)(gr + r) * Cc + gc] = acc[i][j][r] + bv;
    }
  }
}

// ---------------------------------------------------------------------------
extern "C" void kernel_launch(void* const* d_in, const int* in_sizes, int n_in,
                              void* d_out, int out_size, void* d_ws,
                              size_t ws_size, hipStream_t stream) {
  const float* x = (const float*)d_in[0];
  const float* qkv_w = (const float*)d_in[1];
  const float* proj_w = (const float*)d_in[2];
  const float* proj_b = (const float*)d_in[3];
  const float* rand_matrix = (const float*)d_in[4];
  const float* learned_k = (const float*)d_in[5];
  const float* learned_lam = (const float*)d_in[6];
  const float* learned_L = (const float*)d_in[7];
  float* out = (float*)d_out;

  const size_t SX = 25165824;   // x_bf / attn_bf (aliased)
  const size_t SQF = 50331648;  // qf_t
  const size_t SVT = 25165824;  // vb_t
  const size_t SXT = 3145728;   // xss_t
  const size_t SW = 1179648;    // w_bf
  const size_t SPW = 589824;    // pw_bf
  const size_t SRT = 98304;     // rand_t
  const size_t U16TOT = SX + SQF + SVT + SXT + SW + SPW + SRT;
  const size_t SKK = 6291456, SIN = 3145728, SNM = 49152, SLB = 384;
  const size_t need = U16TOT * 2 + (SKK + SIN + SNM + SLB) * 4;
  if (ws_size < need) return;  // graceful fail rather than OOB crash

  u16* xbf = (u16*)d_ws;
  u16* qft = xbf + SX;
  u16* vbt = qft + SQF;
  u16* xsst = vbt + SVT;
  u16* wbf = xsst + SXT;
  u16* pwbf = wbf + SW;
  u16* randt = pwbf + SPW;
  float* kkf = (float*)(randt + SRT);
  float* inpf = kkf + SKK;
  float* normsf = inpf + SIN;
  float* Lb = normsf + SNM;
  u16* attnbf = xbf;  // alias: x_bf dead after qkv

  prep_kernel<<<2048, 256, 0, stream>>>(x, qkv_w, proj_w, rand_matrix, xbf,
                                        wbf, pwbf, randt);
  qkv_qf_kernel<<<dim3(256, 12), 256, 0, stream>>>(xbf, wbf, randt, qft, vbt);
  kk_inp_kernel<<<Bc * Hc, 384, 0, stream>>>(qft, vbt, kkf, inpf);
  norm_kernel<<<Bc * Hc, 256, 0, stream>>>(kkf, inpf, normsf, Lb);
  kkl_kernel<<<Bc * Hc, 256, 0, stream>>>(kkf, learned_k);
  ista_kernel<<<Bc * Hc, 256, 0, stream>>>(kkf, inpf, normsf, Lb, learned_lam,
                                           learned_L, xsst);
  pvout_kernel<<<dim3(Bc * Hc, Nc / 128), 256, 0, stream>>>(qft, xsst, attnbf);
  proj_kernel<<<dim3(256, 6), 256, 0, stream>>>(attnbf, pwbf, proj_b, out);
}

// Round 6
// 631.375 us; speedup vs baseline: 1.2602x; 1.1665x over previous
//
#include <hip/hip_runtime.h>
#include <math.h>

typedef unsigned short u16;
typedef unsigned int u32;
typedef __attribute__((ext_vector_type(8))) short bf16x8;
typedef __attribute__((ext_vector_type(4))) float f32x4;

constexpr int Bc = 32, Nc = 1024, Cc = 768, Hc = 12, HDc = 64, Mc = 128;
constexpr int NUM_STEP_C = 8;
constexpr float QSCALE = 0.35355339059327376f;      // 8^-0.5
constexpr float INV_SQRT_M = 0.088388347648318447f; // 1/sqrt(128)
constexpr float EPSC = 1e-12f;

__device__ __forceinline__ float softf(float z, float thr) {
  float az = fabsf(z) - thr;
  float g = 0.5f * az * (1.0f + erff(az * 0.70710678118654752f));
  return (z > 0.f) ? g : ((z < 0.f) ? -g : 0.f);
}

__device__ __forceinline__ u16 f2bf(float f) {
  u32 u = __float_as_uint(f);
  u += 0x7fffu + ((u >> 16) & 1u);
  return (u16)(u >> 16);
}

__device__ __forceinline__ f32x4 fzero() {
  f32x4 z; z[0] = 0.f; z[1] = 0.f; z[2] = 0.f; z[3] = 0.f; return z;
}

__device__ __forceinline__ f32x4 mfma16(bf16x8 a, bf16x8 b, f32x4 c) {
  return __builtin_amdgcn_mfma_f32_16x16x32_bf16(a, b, c, 0, 0, 0);
}

// Swizzled read offset within a [*][64]-u16 LDS tile: col(u16) XOR'ed by row
#define SWZ_COL(col, row) ((col) ^ (((row) & 7) << 3))

// Stage 32 rows x 64 u16 of a row-major (ld elems) global tile into linear
// LDS [.][64]; inverse swizzle pre-applied to the GLOBAL source (rule #21).
__device__ __forceinline__ void stage_swz(const u16* __restrict__ g, int ld,
                                          u16* lds, int w, int lane) {
  const int rr = lane >> 3;                 // 0..7 row within 8-row call
  const int cs = ((lane & 7) ^ rr) << 3;    // pre-swizzled col (u16)
#pragma unroll
  for (int c = 0; c < 4; ++c) {
    const int r0 = w * 32 + c * 8;
    __builtin_amdgcn_global_load_lds(
        (const __attribute__((address_space(1))) void*)(g + (size_t)(r0 + rr) * ld + cs),
        (__attribute__((address_space(3))) void*)(lds + r0 * 64), 16, 0, 0);
  }
}

// ---------------------------------------------------------------------------
// prep: f32 -> bf16 conversions (x, qkv_w, proj_w) + rand_matrix transpose
// ---------------------------------------------------------------------------
__global__ __launch_bounds__(256) void prep_kernel(
    const float* __restrict__ x, const float* __restrict__ qw,
    const float* __restrict__ pw, const float* __restrict__ rnd,
    u16* __restrict__ xbf, u16* __restrict__ wbf, u16* __restrict__ pwbf,
    u16* __restrict__ randt) {
  const int NX8 = 3145728, NW8 = 147456, NP8 = 73728, NR = 98304;
  const int total = NX8 + NW8 + NP8 + NR;
  for (int idx = blockIdx.x * 256 + threadIdx.x; idx < total;
       idx += gridDim.x * 256) {
    if (idx < NX8 + NW8 + NP8) {
      const float* src; u16* dst; int k;
      if (idx < NX8) { src = x; dst = xbf; k = idx; }
      else if (idx < NX8 + NW8) { src = qw; dst = wbf; k = idx - NX8; }
      else { src = pw; dst = pwbf; k = idx - NX8 - NW8; }
      float4 a = *(const float4*)(src + (size_t)k * 8);
      float4 b = *(const float4*)(src + (size_t)k * 8 + 4);
      uint4 o;
      o.x = (u32)f2bf(a.x) | ((u32)f2bf(a.y) << 16);
      o.y = (u32)f2bf(a.z) | ((u32)f2bf(a.w) << 16);
      o.z = (u32)f2bf(b.x) | ((u32)f2bf(b.y) << 16);
      o.w = (u32)f2bf(b.z) | ((u32)f2bf(b.w) << 16);
      *(uint4*)(dst + (size_t)k * 8) = o;
    } else {
      int k = idx - NX8 - NW8 - NP8;           // rand_t[h][m][d]
      int h = k >> 13, rem = k & 8191, m = rem >> 6, d = rem & 63;
      randt[k] = f2bf(rnd[(size_t)h * 8192 + d * 128 + m]);
    }
  }
}

// ---------------------------------------------------------------------------
// Fused QKV MFMA GEMM + qf epilogue. BK=64, 2-phase double-buffered
// global_load_lds staging (T3-minimum), XCD-swizzled grid.
// bj<6: q -> qf_t (bf16 [B,H,M,N]); bj>=6: v -> vb_t (bf16 [B,H,HD,N]).
// ---------------------------------------------------------------------------
__global__ __launch_bounds__(256) void qkv_qf_kernel(
    const u16* __restrict__ xbf, const u16* __restrict__ wbf,
    const u16* __restrict__ randt, u16* __restrict__ qft,
    u16* __restrict__ vbt) {
  // dbuf: [cur*16384]: A(8192) | B(8192); epilogue reuses as Qls[2][128][72]
  __shared__ __align__(16) u16 SH[32768];
  const int t = threadIdx.x;
  // bijective XCD swizzle: 3072 blocks = 8 * 384; bj fastest within bi
  const int hblk = blockIdx.x;
  const int lin = (hblk & 7) * 384 + (hblk >> 3);
  const int bi = lin / 12, bj = lin % 12;
  const int w = t >> 6, lane = t & 63, ln = lane & 15, kg = lane >> 4;
  const int wr = w >> 1, wc = w & 1;
  f32x4 acc[4][4];
#pragma unroll
  for (int i = 0; i < 4; ++i)
#pragma unroll
    for (int j = 0; j < 4; ++j) acc[i][j] = fzero();
  const u16* Ag = xbf + (size_t)(bi * 128) * Cc;
  const u16* Bg = wbf + (size_t)(bj * 128) * Cc;
  stage_swz(Ag, Cc, SH, w, lane);
  stage_swz(Bg, Cc, SH + 8192, w, lane);
  __syncthreads();
  int cur = 0;
  for (int tt = 0; tt < 12; ++tt) {
    if (tt < 11) {
      stage_swz(Ag + (tt + 1) * 64, Cc, SH + (cur ^ 1) * 16384, w, lane);
      stage_swz(Bg + (tt + 1) * 64, Cc, SH + 8192 + (cur ^ 1) * 16384, w, lane);
    }
    const u16* Als = SH + cur * 16384;
    const u16* Bls = SH + 8192 + cur * 16384;
#pragma unroll
    for (int ks = 0; ks < 2; ++ks) {
      const int cb = ks * 32 + kg * 8;
      bf16x8 af[4], bf[4];
#pragma unroll
      for (int i = 0; i < 4; ++i)
        af[i] = *(const bf16x8*)(Als + (wr * 64 + i * 16 + ln) * 64 +
                                 SWZ_COL(cb, ln));
#pragma unroll
      for (int j = 0; j < 4; ++j)
        bf[j] = *(const bf16x8*)(Bls + (wc * 64 + j * 16 + ln) * 64 +
                                 SWZ_COL(cb, ln));
#pragma unroll
      for (int i = 0; i < 4; ++i)
#pragma unroll
        for (int j = 0; j < 4; ++j) acc[i][j] = mfma16(af[i], bf[j], acc[i][j]);
    }
    __syncthreads();
    cur ^= 1;
  }
  const int b = bi >> 3;
  const int ntile = (bi & 7) * 128;
  if (bj >= 6) {
    // ---- V: write transposed bf16 [B,H,64,1024] ----
    const int h = (bj - 6) * 2 + wc;
    u16* vt = vbt + ((size_t)(b * Hc + h) * 64) * 1024;
#pragma unroll
    for (int i = 0; i < 4; ++i)
#pragma unroll
      for (int j = 0; j < 4; ++j) {
        int d = j * 16 + ln;
        int n0 = ntile + wr * 64 + i * 16 + kg * 4;
        uint2 pv;
        pv.x = (u32)f2bf(acc[i][j][0]) | ((u32)f2bf(acc[i][j][1]) << 16);
        pv.y = (u32)f2bf(acc[i][j][2]) | ((u32)f2bf(acc[i][j][3]) << 16);
        *(uint2*)(vt + (size_t)d * 1024 + n0) = pv;
      }
  } else {
    // ---- Q -> qf_t epilogue ----
#pragma unroll
    for (int i = 0; i < 4; ++i)
#pragma unroll
      for (int j = 0; j < 4; ++j) acc[i][j] *= QSCALE;
    float hn[4][4];
#pragma unroll
    for (int i = 0; i < 4; ++i)
#pragma unroll
      for (int r = 0; r < 4; ++r) {
        float s = acc[i][0][r] * acc[i][0][r] + acc[i][1][r] * acc[i][1][r] +
                  acc[i][2][r] * acc[i][2][r] + acc[i][3][r] * acc[i][3][r];
        s += __shfl_xor(s, 1); s += __shfl_xor(s, 2);
        s += __shfl_xor(s, 4); s += __shfl_xor(s, 8);
        hn[i][r] = 0.5f * s;
      }
    // stage q (bf16) to Qls[head][row][d] (row stride 72)
    u16* Qls = SH;
#pragma unroll
    for (int i = 0; i < 4; ++i)
#pragma unroll
      for (int j = 0; j < 4; ++j)
#pragma unroll
        for (int r = 0; r < 4; ++r)
          Qls[(size_t)(wc * 128 + wr * 64 + i * 16 + kg * 4 + r) * 72 +
              j * 16 + ln] = f2bf(acc[i][j][r]);
    __syncthreads();
    // qf GEMM: wave w -> head (w&1), rows (w>>1)*64..+64, K=64
    const int hq = bj * 2 + (w & 1);
    const int r0q = (w >> 1) * 64;
    const u16* rt = randt + (size_t)hq * Mc * HDc;  // [m][64]
    u16* qtb = qft + ((size_t)(b * Hc + hq) * Mc) * Nc;  // [m][n]
    const u16* qsl = Qls + (size_t)(w & 1) * 128 * 72;
#pragma unroll
    for (int mh = 0; mh < 2; ++mh) {
      f32x4 a2[4][4];
#pragma unroll
      for (int i = 0; i < 4; ++i)
#pragma unroll
        for (int j = 0; j < 4; ++j) a2[i][j] = fzero();
#pragma unroll
      for (int ks = 0; ks < 2; ++ks) {
        bf16x8 af[4], bfr[4];
#pragma unroll
        for (int i = 0; i < 4; ++i)
          af[i] = *(const bf16x8*)(qsl + (size_t)(r0q + i * 16 + ln) * 72 +
                                   ks * 32 + kg * 8);
#pragma unroll
        for (int j = 0; j < 4; ++j)
          bfr[j] = *(const bf16x8*)(rt +
                                    (size_t)(mh * 64 + j * 16 + ln) * 64 +
                                    ks * 32 + kg * 8);
#pragma unroll
        for (int i = 0; i < 4; ++i)
#pragma unroll
          for (int j = 0; j < 4; ++j)
            a2[i][j] = mfma16(af[i], bfr[j], a2[i][j]);
      }
      // qf_t[m][n] stores: uint2 = 4 consecutive n per (i,j)
#pragma unroll
      for (int i = 0; i < 4; ++i)
#pragma unroll
        for (int j = 0; j < 4; ++j) {
          const int m = mh * 64 + j * 16 + ln;
          const int n0 = ntile + r0q + i * 16 + kg * 4;
          float e0 = expf(a2[i][j][0] - hn[i][0]) * INV_SQRT_M;
          float e1 = expf(a2[i][j][1] - hn[i][1]) * INV_SQRT_M;
          float e2 = expf(a2[i][j][2] - hn[i][2]) * INV_SQRT_M;
          float e3 = expf(a2[i][j][3] - hn[i][3]) * INV_SQRT_M;
          uint2 pv;
          pv.x = (u32)f2bf(e0) | ((u32)f2bf(e1) << 16);
          pv.y = (u32)f2bf(e2) | ((u32)f2bf(e3) << 16);
          *(uint2*)(qtb + (size_t)m * Nc + n0) = pv;
        }
    }
  }
}

// ---------------------------------------------------------------------------
// kk_inp: per bh, C[128 x 192] = qf_t . [qf_t | vbt]^T over n (K = 1024).
// 2-phase double-buffered staging. 384 thr, 6 waves.
// ---------------------------------------------------------------------------
__global__ __launch_bounds__(384) void kk_inp_kernel(
    const u16* __restrict__ qft, const u16* __restrict__ vbt,
    float* __restrict__ kk, float* __restrict__ inp) {
  // dbuf: [cur*12288]: At(8192) | Vt(4096)  -> 48 KB total
  __shared__ __align__(16) u16 SH[24576];
  const int t = threadIdx.x, bh = blockIdx.x;
  const int w = t >> 6, lane = t & 63, ln = lane & 15, kg = lane >> 4;
  const int wr = w / 3, wc = w % 3;
  const u16* qg = qft + (size_t)bh * Mc * Nc;   // [m][n]
  const u16* vg = vbt + (size_t)bh * 64 * Nc;   // [d][n]
  const int rr = lane >> 3;
  const int cs = ((lane & 7) ^ rr) << 3;
  f32x4 acc[4][4];
#pragma unroll
  for (int i = 0; i < 4; ++i)
#pragma unroll
    for (int j = 0; j < 4; ++j) acc[i][j] = fzero();

  auto stage = [&](int kt, int buf) {
    u16* Atl = SH + buf * 12288;
    u16* Vtl = Atl + 8192;
    const int n0 = kt * 64;
#pragma unroll
    for (int q = 0; q < 4; ++q) {
      const int idx = w * 4 + q;   // 0..23: 16 qf_t calls + 8 vbt calls
      if (idx < 16) {
        __builtin_amdgcn_global_load_lds(
            (const __attribute__((address_space(1))) void*)(
                qg + (size_t)(idx * 8 + rr) * Nc + n0 + cs),
            (__attribute__((address_space(3))) void*)(Atl + idx * 8 * 64), 16,
            0, 0);
      } else {
        __builtin_amdgcn_global_load_lds(
            (const __attribute__((address_space(1))) void*)(
                vg + (size_t)((idx - 16) * 8 + rr) * Nc + n0 + cs),
            (__attribute__((address_space(3))) void*)(Vtl + (idx - 16) * 8 * 64),
            16, 0, 0);
      }
    }
  };

  stage(0, 0);
  __syncthreads();
  int cur = 0;
  for (int kt = 0; kt < 16; ++kt) {
    if (kt < 15) stage(kt + 1, cur ^ 1);
    const u16* Atl = SH + cur * 12288;
    const u16* Vtl = Atl + 8192;
#pragma unroll
    for (int ks = 0; ks < 2; ++ks) {
      const int cb = ks * 32 + kg * 8;
      bf16x8 af[4], bf[4];
#pragma unroll
      for (int i = 0; i < 4; ++i)
        af[i] = *(const bf16x8*)(Atl + (wr * 64 + i * 16 + ln) * 64 +
                                 SWZ_COL(cb, ln));
      if (wc < 2) {
#pragma unroll
        for (int j = 0; j < 4; ++j)
          bf[j] = *(const bf16x8*)(Atl + (wc * 64 + j * 16 + ln) * 64 +
                                   SWZ_COL(cb, ln));
      } else {
#pragma unroll
        for (int j = 0; j < 4; ++j)
          bf[j] = *(const bf16x8*)(Vtl + (j * 16 + ln) * 64 + SWZ_COL(cb, ln));
      }
#pragma unroll
      for (int i = 0; i < 4; ++i)
#pragma unroll
        for (int j = 0; j < 4; ++j) acc[i][j] = mfma16(af[i], bf[j], acc[i][j]);
    }
    __syncthreads();
    cur ^= 1;
  }
  if (wc < 2) {
    float* og = kk + (size_t)bh * Mc * Mc;
#pragma unroll
    for (int i = 0; i < 4; ++i)
#pragma unroll
      for (int j = 0; j < 4; ++j)
#pragma unroll
        for (int r = 0; r < 4; ++r)
          og[(size_t)(wr * 64 + i * 16 + kg * 4 + r) * Mc + wc * 64 + j * 16 +
             ln] = acc[i][j][r];
  } else {
    float* og = inp + (size_t)bh * Mc * HDc;
#pragma unroll
    for (int i = 0; i < 4; ++i)
#pragma unroll
      for (int j = 0; j < 4; ++j)
#pragma unroll
        for (int r = 0; r < 4; ++r)
          og[(size_t)(wr * 64 + i * 16 + kg * 4 + r) * HDc + j * 16 + ln] =
              acc[i][j][r];
  }
}

// ---------------------------------------------------------------------------
// normalize in place + L
// ---------------------------------------------------------------------------
__global__ __launch_bounds__(256) void norm_kernel(float* kk, float* inp,
                                                   float* __restrict__ norms,
                                                   float* __restrict__ Lbuf) {
  __shared__ float nrm[128];
  __shared__ float rowsum[128];
  const int t = threadIdx.x, bh = blockIdx.x;
  float* kkg = kk + (size_t)bh * Mc * Mc;
  float* ig = inp + (size_t)bh * Mc * HDc;
  if (t < 128) {
    float nm = fmaxf(sqrtf(kkg[t * Mc + t]), EPSC);
    nrm[t] = nm;
    norms[(size_t)bh * Mc + t] = nm;
  }
  __syncthreads();
#pragma unroll 8
  for (int e = 0; e < 64; ++e) {
    int idx = e * 256 + t;
    int m = idx >> 7, p = idx & 127;
    kkg[idx] = kkg[idx] / (nrm[m] * nrm[p]);
  }
#pragma unroll 8
  for (int e = 0; e < 32; ++e) {
    int idx = e * 256 + t;
    int m = idx >> 6;
    ig[idx] = ig[idx] / nrm[m];
  }
  __syncthreads();
  if (t < 128) {
    float s = 0.f;
    for (int p = 0; p < 128; ++p) s += fabsf(kkg[t * Mc + p]);
    rowsum[t] = s;
  }
  __syncthreads();
  if (t == 0) {
    float mx = rowsum[0];
    for (int i = 1; i < 128; ++i) mx = fmaxf(mx, rowsum[i]);
    Lbuf[bh] = mx + 1.0f;
  }
}

// ---------------------------------------------------------------------------
// kk = learned_k @ kk @ learned_k, in place
// ---------------------------------------------------------------------------
__global__ __launch_bounds__(256) void kkl_kernel(float* kk,
                                                  const float* __restrict__ lk) {
  __shared__ float Ks[128][132];
  __shared__ float Xs[128][132];
  const int t = threadIdx.x, bh = blockIdx.x;
  float* kg = kk + (size_t)bh * Mc * Mc;
#pragma unroll
  for (int c = 0; c < 16; ++c) {
    int lin = c * 1024 + t * 4;
    int r = lin >> 7, cc = lin & 127;
    float4 a = *(const float4*)(lk + lin);
    Ks[r][cc] = a.x; Ks[r][cc + 1] = a.y; Ks[r][cc + 2] = a.z; Ks[r][cc + 3] = a.w;
    float4 b = *(const float4*)(kg + lin);
    Xs[r][cc] = b.x; Xs[r][cc + 1] = b.y; Xs[r][cc + 2] = b.z; Xs[r][cc + 3] = b.w;
  }
  __syncthreads();
  const int rg = t >> 3, cgp = t & 7;
  const int r0 = rg * 4, c0 = cgp * 16;
  float tmp[4][16] = {};
  for (int p = 0; p < 128; ++p) {
    float kv[4];
#pragma unroll
    for (int i = 0; i < 4; ++i) kv[i] = Ks[r0 + i][p];
    float xv[16];
#pragma unroll
    for (int j = 0; j < 4; ++j)
      *(float4*)&xv[j * 4] = *(const float4*)&Xs[p][c0 + j * 4];
#pragma unroll
    for (int i = 0; i < 4; ++i)
#pragma unroll
      for (int j = 0; j < 16; ++j) tmp[i][j] = fmaf(kv[i], xv[j], tmp[i][j]);
  }
  __syncthreads();
#pragma unroll
  for (int i = 0; i < 4; ++i)
#pragma unroll
    for (int j = 0; j < 4; ++j)
      *(float4*)&Xs[r0 + i][c0 + j * 4] = *(float4*)&tmp[i][j * 4];
  __syncthreads();
  float acc[4][16] = {};
  for (int p = 0; p < 128; ++p) {
    float kv[4];
#pragma unroll
    for (int i = 0; i < 4; ++i) kv[i] = Xs[r0 + i][p];
    float xv[16];
#pragma unroll
    for (int j = 0; j < 4; ++j)
      *(float4*)&xv[j * 4] = *(const float4*)&Ks[p][c0 + j * 4];
#pragma unroll
    for (int i = 0; i < 4; ++i)
#pragma unroll
      for (int j = 0; j < 16; ++j) acc[i][j] = fmaf(kv[i], xv[j], acc[i][j]);
  }
#pragma unroll
  for (int i = 0; i < 4; ++i)
#pragma unroll
    for (int j = 0; j < 4; ++j)
      *(float4*)(kg + (size_t)(r0 + i) * Mc + c0 + j * 4) = *(float4*)&acc[i][j * 4];
}

// ---------------------------------------------------------------------------
// ISTA; epilogue writes xss_t bf16 [B,H,64,128]
// ---------------------------------------------------------------------------
__global__ __launch_bounds__(256) void ista_kernel(
    const float* __restrict__ kkl, const float* __restrict__ inp,
    const float* __restrict__ norms, const float* __restrict__ Lbuf,
    const float* __restrict__ lamp, const float* __restrict__ Lp,
    u16* __restrict__ xsst) {
  __shared__ float kks[128][129];
  __shared__ float xs[128][64];
  const int t = threadIdx.x, bh = blockIdx.x;
  const float* kg = kkl + (size_t)bh * Mc * Mc;
#pragma unroll
  for (int c = 0; c < 16; ++c) {
    int lin = c * 1024 + t * 4;
    int r = lin >> 7, cc = lin & 127;
    float4 a = *(const float4*)(kg + lin);
    kks[r][cc] = a.x; kks[r][cc + 1] = a.y; kks[r][cc + 2] = a.z; kks[r][cc + 3] = a.w;
  }
  const float lam = lamp[0] * 0.1f;
  const float Ll = Lbuf[bh] / Lp[0];
  const float thr = lam / Ll;
  const float invLl = 1.0f / Ll;
  const int mg = t >> 3, dg = t & 7;
  const int m0 = mg * 4, d0 = dg * 8;
  const float* ig = inp + (size_t)bh * Mc * HDc;
  float ri[4][8], xr[4][8];
#pragma unroll
  for (int i = 0; i < 4; ++i) {
    *(float4*)&ri[i][0] = *(const float4*)(ig + (size_t)(m0 + i) * HDc + d0);
    *(float4*)&ri[i][4] = *(const float4*)(ig + (size_t)(m0 + i) * HDc + d0 + 4);
  }
#pragma unroll
  for (int i = 0; i < 4; ++i)
#pragma unroll
    for (int j = 0; j < 8; ++j) xr[i][j] = softf(ri[i][j], lam);
#pragma unroll
  for (int i = 0; i < 4; ++i) {
    *(float4*)&xs[m0 + i][d0] = *(float4*)&xr[i][0];
    *(float4*)&xs[m0 + i][d0 + 4] = *(float4*)&xr[i][4];
  }
  __syncthreads();
  for (int s = 0; s < NUM_STEP_C; ++s) {
    float acc[4][8] = {};
    for (int p = 0; p < 128; ++p) {
      float kv[4];
#pragma unroll
      for (int i = 0; i < 4; ++i) kv[i] = kks[m0 + i][p];
      float xv[8];
      *(float4*)&xv[0] = *(const float4*)&xs[p][d0];
      *(float4*)&xv[4] = *(const float4*)&xs[p][d0 + 4];
#pragma unroll
      for (int i = 0; i < 4; ++i)
#pragma unroll
        for (int j = 0; j < 8; ++j) acc[i][j] = fmaf(kv[i], xv[j], acc[i][j]);
    }
#pragma unroll
    for (int i = 0; i < 4; ++i)
#pragma unroll
      for (int j = 0; j < 8; ++j)
        xr[i][j] = softf(xr[i][j] - (acc[i][j] - ri[i][j]) * invLl, thr);
    __syncthreads();
#pragma unroll
    for (int i = 0; i < 4; ++i) {
      *(float4*)&xs[m0 + i][d0] = *(float4*)&xr[i][0];
      *(float4*)&xs[m0 + i][d0 + 4] = *(float4*)&xr[i][4];
    }
    __syncthreads();
  }
  u16* og = xsst + (size_t)bh * HDc * Mc;
  float invn[4];
#pragma unroll
  for (int i = 0; i < 4; ++i)
    invn[i] = 1.0f / norms[(size_t)bh * Mc + m0 + i];
#pragma unroll
  for (int j = 0; j < 8; ++j) {
    uint2 pv;
    pv.x = (u32)f2bf(xr[0][j] * invn[0]) | ((u32)f2bf(xr[1][j] * invn[1]) << 16);
    pv.y = (u32)f2bf(xr[2][j] * invn[2]) | ((u32)f2bf(xr[3][j] * invn[3]) << 16);
    *(uint2*)(og + (size_t)(d0 + j) * Mc + m0) = pv;
  }
}

// ---------------------------------------------------------------------------
// pvout: attn_bf[b*N+n][h*64+d] = sum_m qf_t[bh][m][n] * xss_t[bh][d][m]
// Global-direct TN; no LDS, no barriers.
// ---------------------------------------------------------------------------
__global__ __launch_bounds__(256) void pvout_kernel(
    const u16* __restrict__ qft, const u16* __restrict__ xsst,
    u16* __restrict__ attn) {
  const int t = threadIdx.x;
  const int bh = blockIdx.x, nt = blockIdx.y;
  const int b = bh / Hc, h = bh % Hc;
  const int w = t >> 6, lane = t & 63, ln = lane & 15, kg = lane >> 4;
  const u16* qt = qft + (size_t)bh * Mc * Nc;   // [m][n]
  const u16* xg = xsst + (size_t)bh * HDc * Mc; // [d][m]
  f32x4 acc[2][4];
#pragma unroll
  for (int i = 0; i < 2; ++i)
#pragma unroll
    for (int j = 0; j < 4; ++j) acc[i][j] = fzero();
#pragma unroll
  for (int ks = 0; ks < 4; ++ks) {
    const int m8 = ks * 32 + kg * 8;
    bf16x8 af[2];
#pragma unroll
    for (int i = 0; i < 2; ++i) {
      const int n = nt * 128 + w * 32 + i * 16 + ln;
      const u16* p = qt + (size_t)m8 * Nc + n;
#pragma unroll
      for (int e = 0; e < 8; ++e) af[i][e] = (short)p[(size_t)e * Nc];
    }
    bf16x8 bf[4];
#pragma unroll
    for (int j = 0; j < 4; ++j)
      bf[j] = *(const bf16x8*)(xg + (size_t)(j * 16 + ln) * Mc + m8);
#pragma unroll
    for (int i = 0; i < 2; ++i)
#pragma unroll
      for (int j = 0; j < 4; ++j) acc[i][j] = mfma16(af[i], bf[j], acc[i][j]);
  }
#pragma unroll
  for (int i = 0; i < 2; ++i)
#pragma unroll
    for (int j = 0; j < 4; ++j)
#pragma unroll
      for (int r = 0; r < 4; ++r) {
        int n = nt * 128 + w * 32 + i * 16 + kg * 4 + r;
        attn[((size_t)(b * Nc + n)) * Cc + h * 64 + j * 16 + ln] =
            f2bf(acc[i][j][r]);
      }
}

// ---------------------------------------------------------------------------
// proj: out[i][j] = sum_k attn_bf[i][k] * pwbf[j][k] + bias[j]  (f32 out)
// BK=64, 2-phase double-buffered staging, XCD-swizzled grid.
// ---------------------------------------------------------------------------
__global__ __launch_bounds__(256) void proj_kernel(
    const u16* __restrict__ abf, const u16* __restrict__ pwbf,
    const float* __restrict__ bias, float* __restrict__ out) {
  __shared__ __align__(16) u16 SH[32768];
  const int t = threadIdx.x;
  // bijective XCD swizzle: 1536 blocks = 8 * 192; bj fastest within bi
  const int hblk = blockIdx.x;
  const int lin = (hblk & 7) * 192 + (hblk >> 3);
  const int bi = lin / 6, bj = lin % 6;
  const int w = t >> 6, lane = t & 63, ln = lane & 15, kg = lane >> 4;
  const int wr = w >> 1, wc = w & 1;
  f32x4 acc[4][4];
#pragma unroll
  for (int i = 0; i < 4; ++i)
#pragma unroll
    for (int j = 0; j < 4; ++j) acc[i][j] = fzero();
  const u16* Ag = abf + (size_t)(bi * 128) * Cc;
  const u16* Bg = pwbf + (size_t)(bj * 128) * Cc;
  stage_swz(Ag, Cc, SH, w, lane);
  stage_swz(Bg, Cc, SH + 8192, w, lane);
  __syncthreads();
  int cur = 0;
  for (int tt = 0; tt < 12; ++tt) {
    if (tt < 11) {
      stage_swz(Ag + (tt + 1) * 64, Cc, SH + (cur ^ 1) * 16384, w, lane);
      stage_swz(Bg + (tt + 1) * 64, Cc, SH + 8192 + (cur ^ 1) * 16384, w, lane);
    }
    const u16* Als = SH + cur * 16384;
    const u16* Bls = SH + 8192 + cur * 16384;
#pragma unroll
    for (int ks = 0; ks < 2; ++ks) {
      const int cb = ks * 32 + kg * 8;
      bf16x8 af[4], bf[4];
#pragma unroll
      for (int i = 0; i < 4; ++i)
        af[i] = *(const bf16x8*)(Als + (wr * 64 + i * 16 + ln) * 64 +
                                 SWZ_COL(cb, ln));
#pragma unroll
      for (int j = 0; j < 4; ++j)
        bf[j] = *(const bf16x8*)(Bls + (wc * 64 + j * 16 + ln) * 64 +
                                 SWZ_COL(cb, ln));
#pragma unroll
      for (int i = 0; i < 4; ++i)
#pragma unroll
        for (int j = 0; j < 4; ++j) acc[i][j] = mfma16(af[i], bf[j], acc[i][j]);
    }
    __syncthreads();
    cur ^= 1;
  }
#pragma unroll
  for (int j = 0; j < 4; ++j) {
    const int gc = bj * 128 + wc * 64 + j * 16 + ln;
    const float bv = bias[gc];
#pragma unroll
    for (int i = 0; i < 4; ++i) {
      const int gr = bi * 128 + wr * 64 + i * 16 + kg * 4;
#pragma unroll
      for (int r = 0; r < 4; ++r)
        out[(size_t)(gr + r) * Cc + gc] = acc[i][j][r] + bv;
    }
  }
}

// ---------------------------------------------------------------------------
extern "C" void kernel_launch(void* const* d_in, const int* in_sizes, int n_in,
                              void* d_out, int out_size, void* d_ws,
                              size_t ws_size, hipStream_t stream) {
  const float* x = (const float*)d_in[0];
  const float* qkv_w = (const float*)d_in[1];
  const float* proj_w = (const float*)d_in[2];
  const float* proj_b = (const float*)d_in[3];
  const float* rand_matrix = (const float*)d_in[4];
  const float* learned_k = (const float*)d_in[5];
  const float* learned_lam = (const float*)d_in[6];
  const float* learned_L = (const float*)d_in[7];
  float* out = (float*)d_out;

  const size_t SX = 25165824;   // x_bf / attn_bf (aliased)
  const size_t SQF = 50331648;  // qf_t
  const size_t SVT = 25165824;  // vb_t
  const size_t SXT = 3145728;   // xss_t
  const size_t SW = 1179648;    // w_bf
  const size_t SPW = 589824;    // pw_bf
  const size_t SRT = 98304;     // rand_t
  const size_t U16TOT = SX + SQF + SVT + SXT + SW + SPW + SRT;
  const size_t SKK = 6291456, SIN = 3145728, SNM = 49152, SLB = 384;
  const size_t need = U16TOT * 2 + (SKK + SIN + SNM + SLB) * 4;
  if (ws_size < need) return;  // graceful fail rather than OOB crash

  u16* xbf = (u16*)d_ws;
  u16* qft = xbf + SX;
  u16* vbt = qft + SQF;
  u16* xsst = vbt + SVT;
  u16* wbf = xsst + SXT;
  u16* pwbf = wbf + SW;
  u16* randt = pwbf + SPW;
  float* kkf = (float*)(randt + SRT);
  float* inpf = kkf + SKK;
  float* normsf = inpf + SIN;
  float* Lb = normsf + SNM;
  u16* attnbf = xbf;  // alias: x_bf dead after qkv

  prep_kernel<<<2048, 256, 0, stream>>>(x, qkv_w, proj_w, rand_matrix, xbf,
                                        wbf, pwbf, randt);
  qkv_qf_kernel<<<3072, 256, 0, stream>>>(xbf, wbf, randt, qft, vbt);
  kk_inp_kernel<<<Bc * Hc, 384, 0, stream>>>(qft, vbt, kkf, inpf);
  norm_kernel<<<Bc * Hc, 256, 0, stream>>>(kkf, inpf, normsf, Lb);
  kkl_kernel<<<Bc * Hc, 256, 0, stream>>>(kkf, learned_k);
  ista_kernel<<<Bc * Hc, 256, 0, stream>>>(kkf, inpf, normsf, Lb, learned_lam,
                                           learned_L, xsst);
  pvout_kernel<<<dim3(Bc * Hc, Nc / 128), 256, 0, stream>>>(qft, xsst, attnbf);
  proj_kernel<<<1536, 256, 0, stream>>>(attnbf, pwbf, proj_b, out);
}

// Round 7
// 590.264 us; speedup vs baseline: 1.3480x; 1.0696x over previous
//
#include <hip/hip_runtime.h>
#include <math.h>

typedef unsigned short u16;
typedef unsigned int u32;
typedef __attribute__((ext_vector_type(8))) short bf16x8;
typedef __attribute__((ext_vector_type(4))) float f32x4;

constexpr int Bc = 32, Nc = 1024, Cc = 768, Hc = 12, HDc = 64, Mc = 128;
constexpr int NUM_STEP_C = 8;
constexpr float QSCALE = 0.35355339059327376f;      // 8^-0.5
constexpr float INV_SQRT_M = 0.088388347648318447f; // 1/sqrt(128)
constexpr float EPSC = 1e-12f;

__device__ __forceinline__ float softf(float z, float thr) {
  float az = fabsf(z) - thr;
  float g = 0.5f * az * (1.0f + erff(az * 0.70710678118654752f));
  return (z > 0.f) ? g : ((z < 0.f) ? -g : 0.f);
}

__device__ __forceinline__ u16 f2bf(float f) {
  u32 u = __float_as_uint(f);
  u += 0x7fffu + ((u >> 16) & 1u);
  return (u16)(u >> 16);
}

__device__ __forceinline__ f32x4 fzero() {
  f32x4 z; z[0] = 0.f; z[1] = 0.f; z[2] = 0.f; z[3] = 0.f; return z;
}

__device__ __forceinline__ f32x4 mfma16(bf16x8 a, bf16x8 b, f32x4 c) {
  return __builtin_amdgcn_mfma_f32_16x16x32_bf16(a, b, c, 0, 0, 0);
}

// Swizzled read offset within a [*][64]-u16 LDS tile: col(u16) XOR'ed by row
#define SWZ_COL(col, row) ((col) ^ (((row) & 7) << 3))

// Stage 32 rows x 64 u16 of a row-major (ld elems) global tile into linear
// LDS [.][64]; inverse swizzle pre-applied to the GLOBAL source (rule #21).
__device__ __forceinline__ void stage_swz(const u16* __restrict__ g, int ld,
                                          u16* lds, int w, int lane) {
  const int rr = lane >> 3;                 // 0..7 row within 8-row call
  const int cs = ((lane & 7) ^ rr) << 3;    // pre-swizzled col (u16)
#pragma unroll
  for (int c = 0; c < 4; ++c) {
    const int r0 = w * 32 + c * 8;
    __builtin_amdgcn_global_load_lds(
        (const __attribute__((address_space(1))) void*)(g + (size_t)(r0 + rr) * ld + cs),
        (__attribute__((address_space(3))) void*)(lds + r0 * 64), 16, 0, 0);
  }
}

// ---------------------------------------------------------------------------
// prep: f32 -> bf16 conversions (x, qkv_w, proj_w) + rand_matrix transpose
// ---------------------------------------------------------------------------
__global__ __launch_bounds__(256) void prep_kernel(
    const float* __restrict__ x, const float* __restrict__ qw,
    const float* __restrict__ pw, const float* __restrict__ rnd,
    u16* __restrict__ xbf, u16* __restrict__ wbf, u16* __restrict__ pwbf,
    u16* __restrict__ randt) {
  const int NX8 = 3145728, NW8 = 147456, NP8 = 73728, NR = 98304;
  const int total = NX8 + NW8 + NP8 + NR;
  for (int idx = blockIdx.x * 256 + threadIdx.x; idx < total;
       idx += gridDim.x * 256) {
    if (idx < NX8 + NW8 + NP8) {
      const float* src; u16* dst; int k;
      if (idx < NX8) { src = x; dst = xbf; k = idx; }
      else if (idx < NX8 + NW8) { src = qw; dst = wbf; k = idx - NX8; }
      else { src = pw; dst = pwbf; k = idx - NX8 - NW8; }
      float4 a = *(const float4*)(src + (size_t)k * 8);
      float4 b = *(const float4*)(src + (size_t)k * 8 + 4);
      uint4 o;
      o.x = (u32)f2bf(a.x) | ((u32)f2bf(a.y) << 16);
      o.y = (u32)f2bf(a.z) | ((u32)f2bf(a.w) << 16);
      o.z = (u32)f2bf(b.x) | ((u32)f2bf(b.y) << 16);
      o.w = (u32)f2bf(b.z) | ((u32)f2bf(b.w) << 16);
      *(uint4*)(dst + (size_t)k * 8) = o;
    } else {
      int k = idx - NX8 - NW8 - NP8;           // rand_t[h][m][d]
      int h = k >> 13, rem = k & 8191, m = rem >> 6, d = rem & 63;
      randt[k] = f2bf(rnd[(size_t)h * 8192 + d * 128 + m]);
    }
  }
}

// ---------------------------------------------------------------------------
// Fused QKV MFMA GEMM + qf epilogue. BK=64, 2-phase double-buffered
// global_load_lds staging, XCD-swizzled grid, __expf epilogue.
// bj<6: q -> qf_t (bf16 [B,H,M,N]); bj>=6: v -> vb_t (bf16 [B,H,HD,N]).
// ---------------------------------------------------------------------------
__global__ __launch_bounds__(256) void qkv_qf_kernel(
    const u16* __restrict__ xbf, const u16* __restrict__ wbf,
    const u16* __restrict__ randt, u16* __restrict__ qft,
    u16* __restrict__ vbt) {
  // dbuf: [cur*16384]: A(8192) | B(8192); epilogue reuses as Qls[2][128][72]
  __shared__ __align__(16) u16 SH[32768];
  const int t = threadIdx.x;
  // bijective XCD swizzle: 3072 blocks = 8 * 384; bj fastest within bi
  const int hblk = blockIdx.x;
  const int lin = (hblk & 7) * 384 + (hblk >> 3);
  const int bi = lin / 12, bj = lin % 12;
  const int w = t >> 6, lane = t & 63, ln = lane & 15, kg = lane >> 4;
  const int wr = w >> 1, wc = w & 1;
  f32x4 acc[4][4];
#pragma unroll
  for (int i = 0; i < 4; ++i)
#pragma unroll
    for (int j = 0; j < 4; ++j) acc[i][j] = fzero();
  const u16* Ag = xbf + (size_t)(bi * 128) * Cc;
  const u16* Bg = wbf + (size_t)(bj * 128) * Cc;
  stage_swz(Ag, Cc, SH, w, lane);
  stage_swz(Bg, Cc, SH + 8192, w, lane);
  __syncthreads();
  int cur = 0;
  for (int tt = 0; tt < 12; ++tt) {
    if (tt < 11) {
      stage_swz(Ag + (tt + 1) * 64, Cc, SH + (cur ^ 1) * 16384, w, lane);
      stage_swz(Bg + (tt + 1) * 64, Cc, SH + 8192 + (cur ^ 1) * 16384, w, lane);
    }
    const u16* Als = SH + cur * 16384;
    const u16* Bls = SH + 8192 + cur * 16384;
#pragma unroll
    for (int ks = 0; ks < 2; ++ks) {
      const int cb = ks * 32 + kg * 8;
      bf16x8 af[4], bf[4];
#pragma unroll
      for (int i = 0; i < 4; ++i)
        af[i] = *(const bf16x8*)(Als + (wr * 64 + i * 16 + ln) * 64 +
                                 SWZ_COL(cb, ln));
#pragma unroll
      for (int j = 0; j < 4; ++j)
        bf[j] = *(const bf16x8*)(Bls + (wc * 64 + j * 16 + ln) * 64 +
                                 SWZ_COL(cb, ln));
#pragma unroll
      for (int i = 0; i < 4; ++i)
#pragma unroll
        for (int j = 0; j < 4; ++j) acc[i][j] = mfma16(af[i], bf[j], acc[i][j]);
    }
    __syncthreads();
    cur ^= 1;
  }
  const int b = bi >> 3;
  const int ntile = (bi & 7) * 128;
  if (bj >= 6) {
    // ---- V: write transposed bf16 [B,H,64,1024] ----
    const int h = (bj - 6) * 2 + wc;
    u16* vt = vbt + ((size_t)(b * Hc + h) * 64) * 1024;
#pragma unroll
    for (int i = 0; i < 4; ++i)
#pragma unroll
      for (int j = 0; j < 4; ++j) {
        int d = j * 16 + ln;
        int n0 = ntile + wr * 64 + i * 16 + kg * 4;
        uint2 pv;
        pv.x = (u32)f2bf(acc[i][j][0]) | ((u32)f2bf(acc[i][j][1]) << 16);
        pv.y = (u32)f2bf(acc[i][j][2]) | ((u32)f2bf(acc[i][j][3]) << 16);
        *(uint2*)(vt + (size_t)d * 1024 + n0) = pv;
      }
  } else {
    // ---- Q -> qf_t epilogue ----
#pragma unroll
    for (int i = 0; i < 4; ++i)
#pragma unroll
      for (int j = 0; j < 4; ++j) acc[i][j] *= QSCALE;
    float hn[4][4];
#pragma unroll
    for (int i = 0; i < 4; ++i)
#pragma unroll
      for (int r = 0; r < 4; ++r) {
        float s = acc[i][0][r] * acc[i][0][r] + acc[i][1][r] * acc[i][1][r] +
                  acc[i][2][r] * acc[i][2][r] + acc[i][3][r] * acc[i][3][r];
        s += __shfl_xor(s, 1); s += __shfl_xor(s, 2);
        s += __shfl_xor(s, 4); s += __shfl_xor(s, 8);
        hn[i][r] = 0.5f * s;
      }
    // stage q (bf16) to Qls[head][row][d] (row stride 72)
    u16* Qls = SH;
#pragma unroll
    for (int i = 0; i < 4; ++i)
#pragma unroll
      for (int j = 0; j < 4; ++j)
#pragma unroll
        for (int r = 0; r < 4; ++r)
          Qls[(size_t)(wc * 128 + wr * 64 + i * 16 + kg * 4 + r) * 72 +
              j * 16 + ln] = f2bf(acc[i][j][r]);
    __syncthreads();
    // qf GEMM: wave w -> head (w&1), rows (w>>1)*64..+64, K=64
    const int hq = bj * 2 + (w & 1);
    const int r0q = (w >> 1) * 64;
    const u16* rt = randt + (size_t)hq * Mc * HDc;  // [m][64]
    u16* qtb = qft + ((size_t)(b * Hc + hq) * Mc) * Nc;  // [m][n]
    const u16* qsl = Qls + (size_t)(w & 1) * 128 * 72;
#pragma unroll
    for (int mh = 0; mh < 2; ++mh) {
      f32x4 a2[4][4];
#pragma unroll
      for (int i = 0; i < 4; ++i)
#pragma unroll
        for (int j = 0; j < 4; ++j) a2[i][j] = fzero();
#pragma unroll
      for (int ks = 0; ks < 2; ++ks) {
        bf16x8 af[4], bfr[4];
#pragma unroll
        for (int i = 0; i < 4; ++i)
          af[i] = *(const bf16x8*)(qsl + (size_t)(r0q + i * 16 + ln) * 72 +
                                   ks * 32 + kg * 8);
#pragma unroll
        for (int j = 0; j < 4; ++j)
          bfr[j] = *(const bf16x8*)(rt +
                                    (size_t)(mh * 64 + j * 16 + ln) * 64 +
                                    ks * 32 + kg * 8);
#pragma unroll
        for (int i = 0; i < 4; ++i)
#pragma unroll
          for (int j = 0; j < 4; ++j)
            a2[i][j] = mfma16(af[i], bfr[j], a2[i][j]);
      }
      // qf_t[m][n] stores: uint2 = 4 consecutive n per (i,j)
#pragma unroll
      for (int i = 0; i < 4; ++i)
#pragma unroll
        for (int j = 0; j < 4; ++j) {
          const int m = mh * 64 + j * 16 + ln;
          const int n0 = ntile + r0q + i * 16 + kg * 4;
          float e0 = __expf(a2[i][j][0] - hn[i][0]) * INV_SQRT_M;
          float e1 = __expf(a2[i][j][1] - hn[i][1]) * INV_SQRT_M;
          float e2 = __expf(a2[i][j][2] - hn[i][2]) * INV_SQRT_M;
          float e3 = __expf(a2[i][j][3] - hn[i][3]) * INV_SQRT_M;
          uint2 pv;
          pv.x = (u32)f2bf(e0) | ((u32)f2bf(e1) << 16);
          pv.y = (u32)f2bf(e2) | ((u32)f2bf(e3) << 16);
          *(uint2*)(qtb + (size_t)m * Nc + n0) = pv;
        }
    }
  }
}

// ---------------------------------------------------------------------------
// kk_inp: per bh, C[128 x 192] = qf_t . [qf_t | vbt]^T over n (K = 1024).
// 2-phase double-buffered staging. 384 thr, 6 waves.
// ---------------------------------------------------------------------------
__global__ __launch_bounds__(384) void kk_inp_kernel(
    const u16* __restrict__ qft, const u16* __restrict__ vbt,
    float* __restrict__ kk, float* __restrict__ inp) {
  // dbuf: [cur*12288]: At(8192) | Vt(4096)  -> 48 KB total
  __shared__ __align__(16) u16 SH[24576];
  const int t = threadIdx.x, bh = blockIdx.x;
  const int w = t >> 6, lane = t & 63, ln = lane & 15, kg = lane >> 4;
  const int wr = w / 3, wc = w % 3;
  const u16* qg = qft + (size_t)bh * Mc * Nc;   // [m][n]
  const u16* vg = vbt + (size_t)bh * 64 * Nc;   // [d][n]
  const int rr = lane >> 3;
  const int cs = ((lane & 7) ^ rr) << 3;
  f32x4 acc[4][4];
#pragma unroll
  for (int i = 0; i < 4; ++i)
#pragma unroll
    for (int j = 0; j < 4; ++j) acc[i][j] = fzero();

  auto stage = [&](int kt, int buf) {
    u16* Atl = SH + buf * 12288;
    u16* Vtl = Atl + 8192;
    const int n0 = kt * 64;
#pragma unroll
    for (int q = 0; q < 4; ++q) {
      const int idx = w * 4 + q;   // 0..23: 16 qf_t calls + 8 vbt calls
      if (idx < 16) {
        __builtin_amdgcn_global_load_lds(
            (const __attribute__((address_space(1))) void*)(
                qg + (size_t)(idx * 8 + rr) * Nc + n0 + cs),
            (__attribute__((address_space(3))) void*)(Atl + idx * 8 * 64), 16,
            0, 0);
      } else {
        __builtin_amdgcn_global_load_lds(
            (const __attribute__((address_space(1))) void*)(
                vg + (size_t)((idx - 16) * 8 + rr) * Nc + n0 + cs),
            (__attribute__((address_space(3))) void*)(Vtl + (idx - 16) * 8 * 64),
            16, 0, 0);
      }
    }
  };

  stage(0, 0);
  __syncthreads();
  int cur = 0;
  for (int kt = 0; kt < 16; ++kt) {
    if (kt < 15) stage(kt + 1, cur ^ 1);
    const u16* Atl = SH + cur * 12288;
    const u16* Vtl = Atl + 8192;
#pragma unroll
    for (int ks = 0; ks < 2; ++ks) {
      const int cb = ks * 32 + kg * 8;
      bf16x8 af[4], bf[4];
#pragma unroll
      for (int i = 0; i < 4; ++i)
        af[i] = *(const bf16x8*)(Atl + (wr * 64 + i * 16 + ln) * 64 +
                                 SWZ_COL(cb, ln));
      if (wc < 2) {
#pragma unroll
        for (int j = 0; j < 4; ++j)
          bf[j] = *(const bf16x8*)(Atl + (wc * 64 + j * 16 + ln) * 64 +
                                   SWZ_COL(cb, ln));
      } else {
#pragma unroll
        for (int j = 0; j < 4; ++j)
          bf[j] = *(const bf16x8*)(Vtl + (j * 16 + ln) * 64 + SWZ_COL(cb, ln));
      }
#pragma unroll
      for (int i = 0; i < 4; ++i)
#pragma unroll
        for (int j = 0; j < 4; ++j) acc[i][j] = mfma16(af[i], bf[j], acc[i][j]);
    }
    __syncthreads();
    cur ^= 1;
  }
  if (wc < 2) {
    float* og = kk + (size_t)bh * Mc * Mc;
#pragma unroll
    for (int i = 0; i < 4; ++i)
#pragma unroll
      for (int j = 0; j < 4; ++j)
#pragma unroll
        for (int r = 0; r < 4; ++r)
          og[(size_t)(wr * 64 + i * 16 + kg * 4 + r) * Mc + wc * 64 + j * 16 +
             ln] = acc[i][j][r];
  } else {
    float* og = inp + (size_t)bh * Mc * HDc;
#pragma unroll
    for (int i = 0; i < 4; ++i)
#pragma unroll
      for (int j = 0; j < 4; ++j)
#pragma unroll
        for (int r = 0; r < 4; ++r)
          og[(size_t)(wr * 64 + i * 16 + kg * 4 + r) * HDc + j * 16 + ln] =
              acc[i][j][r];
  }
}

// ---------------------------------------------------------------------------
// solve: fused norm + kkl + ISTA, one block per (b,h), all state in LDS.
// SA = learned_k, later kk_l as [128][129]; SB = kk (norm'd, then tmp), later
// xs[128][64]. Writes xss_t bf16 [B,H,64,128] only.
// ---------------------------------------------------------------------------
__global__ __launch_bounds__(256) void solve_kernel(
    const float* __restrict__ kk, const float* __restrict__ inp,
    const float* __restrict__ lk, const float* __restrict__ lamp,
    const float* __restrict__ Lp, u16* __restrict__ xsst) {
  __shared__ float SA[128 * 132];
  __shared__ float SB[128 * 132];
  __shared__ float nrm[128];
  __shared__ float rowsum[128];
  __shared__ float Lsh;
  const int t = threadIdx.x, bh = blockIdx.x;
  const float* kg = kk + (size_t)bh * Mc * Mc;
#pragma unroll
  for (int c = 0; c < 16; ++c) {
    int lin = c * 1024 + t * 4;
    int r = lin >> 7, cc = lin & 127;
    *(float4*)&SA[r * 132 + cc] = *(const float4*)(lk + lin);
    *(float4*)&SB[r * 132 + cc] = *(const float4*)(kg + lin);
  }
  __syncthreads();
  if (t < 128) nrm[t] = fmaxf(sqrtf(SB[t * 132 + t]), EPSC);
  __syncthreads();
  // normalize kk in LDS
#pragma unroll 8
  for (int e = 0; e < 64; ++e) {
    int idx = e * 256 + t;
    int m = idx >> 7, p = idx & 127;
    SB[m * 132 + p] = SB[m * 132 + p] / (nrm[m] * nrm[p]);
  }
  __syncthreads();
  if (t < 128) {
    float s = 0.f;
    for (int p = 0; p < 128; ++p) s += fabsf(SB[t * 132 + p]);
    rowsum[t] = s;
  }
  __syncthreads();
  if (t == 0) {
    float mx = rowsum[0];
    for (int i = 1; i < 128; ++i) mx = fmaxf(mx, rowsum[i]);
    Lsh = mx + 1.0f;
  }
  __syncthreads();
  // kk_l = K (SA) . kk_n (SB) . K, two in-LDS passes
  const int rg = t >> 3, cgp = t & 7;
  const int r0 = rg * 4, c0 = cgp * 16;
  {
    float tmp[4][16] = {};
    for (int p = 0; p < 128; ++p) {
      float kv[4];
#pragma unroll
      for (int i = 0; i < 4; ++i) kv[i] = SA[(r0 + i) * 132 + p];
      float xv[16];
#pragma unroll
      for (int j = 0; j < 4; ++j)
        *(float4*)&xv[j * 4] = *(const float4*)&SB[p * 132 + c0 + j * 4];
#pragma unroll
      for (int i = 0; i < 4; ++i)
#pragma unroll
        for (int j = 0; j < 16; ++j) tmp[i][j] = fmaf(kv[i], xv[j], tmp[i][j]);
    }
    __syncthreads();
#pragma unroll
    for (int i = 0; i < 4; ++i)
#pragma unroll
      for (int j = 0; j < 4; ++j)
        *(float4*)&SB[(r0 + i) * 132 + c0 + j * 4] = *(float4*)&tmp[i][j * 4];
  }
  __syncthreads();
  float acc2[4][16];
#pragma unroll
  for (int i = 0; i < 4; ++i)
#pragma unroll
    for (int j = 0; j < 16; ++j) acc2[i][j] = 0.f;
  for (int p = 0; p < 128; ++p) {
    float kv[4];
#pragma unroll
    for (int i = 0; i < 4; ++i) kv[i] = SB[(r0 + i) * 132 + p];
    float xv[16];
#pragma unroll
    for (int j = 0; j < 4; ++j)
      *(float4*)&xv[j * 4] = *(const float4*)&SA[p * 132 + c0 + j * 4];
#pragma unroll
    for (int i = 0; i < 4; ++i)
#pragma unroll
      for (int j = 0; j < 16; ++j) acc2[i][j] = fmaf(kv[i], xv[j], acc2[i][j]);
  }
  __syncthreads();  // all SA reads done; SB tmp no longer needed
  // kk_l -> SA as kks[128][129]
#pragma unroll
  for (int i = 0; i < 4; ++i)
#pragma unroll
    for (int j = 0; j < 16; ++j)
      SA[(r0 + i) * 129 + c0 + j] = acc2[i][j];
  __syncthreads();
  // ---- ISTA (kks = SA stride 129, xs = SB stride 64) ----
  const float lam = lamp[0] * 0.1f;
  const float Ll = Lsh / Lp[0];
  const float thr = lam / Ll;
  const float invLl = 1.0f / Ll;
  const int m0 = r0, d0 = cgp * 8;
  const float* ig = inp + (size_t)bh * Mc * HDc;
  float ri[4][8], xr[4][8];
#pragma unroll
  for (int i = 0; i < 4; ++i) {
    const float innm = 1.0f / nrm[m0 + i];
    float4 v0 = *(const float4*)(ig + (size_t)(m0 + i) * HDc + d0);
    float4 v1 = *(const float4*)(ig + (size_t)(m0 + i) * HDc + d0 + 4);
    ri[i][0] = v0.x * innm; ri[i][1] = v0.y * innm;
    ri[i][2] = v0.z * innm; ri[i][3] = v0.w * innm;
    ri[i][4] = v1.x * innm; ri[i][5] = v1.y * innm;
    ri[i][6] = v1.z * innm; ri[i][7] = v1.w * innm;
  }
#pragma unroll
  for (int i = 0; i < 4; ++i)
#pragma unroll
    for (int j = 0; j < 8; ++j) xr[i][j] = softf(ri[i][j], lam);
#pragma unroll
  for (int i = 0; i < 4; ++i) {
    *(float4*)&SB[(m0 + i) * 64 + d0] = *(float4*)&xr[i][0];
    *(float4*)&SB[(m0 + i) * 64 + d0 + 4] = *(float4*)&xr[i][4];
  }
  __syncthreads();
  for (int s = 0; s < NUM_STEP_C; ++s) {
    float acc[4][8] = {};
    for (int p = 0; p < 128; ++p) {
      float kv[4];
#pragma unroll
      for (int i = 0; i < 4; ++i) kv[i] = SA[(m0 + i) * 129 + p];
      float xv[8];
      *(float4*)&xv[0] = *(const float4*)&SB[p * 64 + d0];
      *(float4*)&xv[4] = *(const float4*)&SB[p * 64 + d0 + 4];
#pragma unroll
      for (int i = 0; i < 4; ++i)
#pragma unroll
        for (int j = 0; j < 8; ++j) acc[i][j] = fmaf(kv[i], xv[j], acc[i][j]);
    }
#pragma unroll
    for (int i = 0; i < 4; ++i)
#pragma unroll
      for (int j = 0; j < 8; ++j)
        xr[i][j] = softf(xr[i][j] - (acc[i][j] - ri[i][j]) * invLl, thr);
    __syncthreads();
#pragma unroll
    for (int i = 0; i < 4; ++i) {
      *(float4*)&SB[(m0 + i) * 64 + d0] = *(float4*)&xr[i][0];
      *(float4*)&SB[(m0 + i) * 64 + d0 + 4] = *(float4*)&xr[i][4];
    }
    __syncthreads();
  }
  // write xss_t[d][m] bf16, xss = xr / nrm[m]
  u16* og = xsst + (size_t)bh * HDc * Mc;
  float invn[4];
#pragma unroll
  for (int i = 0; i < 4; ++i) invn[i] = 1.0f / nrm[m0 + i];
#pragma unroll
  for (int j = 0; j < 8; ++j) {
    uint2 pv;
    pv.x = (u32)f2bf(xr[0][j] * invn[0]) | ((u32)f2bf(xr[1][j] * invn[1]) << 16);
    pv.y = (u32)f2bf(xr[2][j] * invn[2]) | ((u32)f2bf(xr[3][j] * invn[3]) << 16);
    *(uint2*)(og + (size_t)(d0 + j) * Mc + m0) = pv;
  }
}

// ---------------------------------------------------------------------------
// pvout: attn_bf[b*N+n][h*64+d] = sum_m qf_t[bh][m][n] * xss_t[bh][d][m]
// Global-direct TN; no LDS, no barriers.
// ---------------------------------------------------------------------------
__global__ __launch_bounds__(256) void pvout_kernel(
    const u16* __restrict__ qft, const u16* __restrict__ xsst,
    u16* __restrict__ attn) {
  const int t = threadIdx.x;
  const int bh = blockIdx.x, nt = blockIdx.y;
  const int b = bh / Hc, h = bh % Hc;
  const int w = t >> 6, lane = t & 63, ln = lane & 15, kg = lane >> 4;
  const u16* qt = qft + (size_t)bh * Mc * Nc;   // [m][n]
  const u16* xg = xsst + (size_t)bh * HDc * Mc; // [d][m]
  f32x4 acc[2][4];
#pragma unroll
  for (int i = 0; i < 2; ++i)
#pragma unroll
    for (int j = 0; j < 4; ++j) acc[i][j] = fzero();
#pragma unroll
  for (int ks = 0; ks < 4; ++ks) {
    const int m8 = ks * 32 + kg * 8;
    bf16x8 af[2];
#pragma unroll
    for (int i = 0; i < 2; ++i) {
      const int n = nt * 128 + w * 32 + i * 16 + ln;
      const u16* p = qt + (size_t)m8 * Nc + n;
#pragma unroll
      for (int e = 0; e < 8; ++e) af[i][e] = (short)p[(size_t)e * Nc];
    }
    bf16x8 bf[4];
#pragma unroll
    for (int j = 0; j < 4; ++j)
      bf[j] = *(const bf16x8*)(xg + (size_t)(j * 16 + ln) * Mc + m8);
#pragma unroll
    for (int i = 0; i < 2; ++i)
#pragma unroll
      for (int j = 0; j < 4; ++j) acc[i][j] = mfma16(af[i], bf[j], acc[i][j]);
  }
#pragma unroll
  for (int i = 0; i < 2; ++i)
#pragma unroll
    for (int j = 0; j < 4; ++j)
#pragma unroll
      for (int r = 0; r < 4; ++r) {
        int n = nt * 128 + w * 32 + i * 16 + kg * 4 + r;
        attn[((size_t)(b * Nc + n)) * Cc + h * 64 + j * 16 + ln] =
            f2bf(acc[i][j][r]);
      }
}

// ---------------------------------------------------------------------------
// proj: out[i][j] = sum_k attn_bf[i][k] * pwbf[j][k] + bias[j]  (f32 out)
// BK=64, 2-phase double-buffered staging, XCD-swizzled grid.
// ---------------------------------------------------------------------------
__global__ __launch_bounds__(256) void proj_kernel(
    const u16* __restrict__ abf, const u16* __restrict__ pwbf,
    const float* __restrict__ bias, float* __restrict__ out) {
  __shared__ __align__(16) u16 SH[32768];
  const int t = threadIdx.x;
  // bijective XCD swizzle: 1536 blocks = 8 * 192; bj fastest within bi
  const int hblk = blockIdx.x;
  const int lin = (hblk & 7) * 192 + (hblk >> 3);
  const int bi = lin / 6, bj = lin % 6;
  const int w = t >> 6, lane = t & 63, ln = lane & 15, kg = lane >> 4;
  const int wr = w >> 1, wc = w & 1;
  f32x4 acc[4][4];
#pragma unroll
  for (int i = 0; i < 4; ++i)
#pragma unroll
    for (int j = 0; j < 4; ++j) acc[i][j] = fzero();
  const u16* Ag = abf + (size_t)(bi * 128) * Cc;
  const u16* Bg = pwbf + (size_t)(bj * 128) * Cc;
  stage_swz(Ag, Cc, SH, w, lane);
  stage_swz(Bg, Cc, SH + 8192, w, lane);
  __syncthreads();
  int cur = 0;
  for (int tt = 0; tt < 12; ++tt) {
    if (tt < 11) {
      stage_swz(Ag + (tt + 1) * 64, Cc, SH + (cur ^ 1) * 16384, w, lane);
      stage_swz(Bg + (tt + 1) * 64, Cc, SH + 8192 + (cur ^ 1) * 16384, w, lane);
    }
    const u16* Als = SH + cur * 16384;
    const u16* Bls = SH + 8192 + cur * 16384;
#pragma unroll
    for (int ks = 0; ks < 2; ++ks) {
      const int cb = ks * 32 + kg * 8;
      bf16x8 af[4], bf[4];
#pragma unroll
      for (int i = 0; i < 4; ++i)
        af[i] = *(const bf16x8*)(Als + (wr * 64 + i * 16 + ln) * 64 +
                                 SWZ_COL(cb, ln));
#pragma unroll
      for (int j = 0; j < 4; ++j)
        bf[j] = *(const bf16x8*)(Bls + (wc * 64 + j * 16 + ln) * 64 +
                                 SWZ_COL(cb, ln));
#pragma unroll
      for (int i = 0; i < 4; ++i)
#pragma unroll
        for (int j = 0; j < 4; ++j) acc[i][j] = mfma16(af[i], bf[j], acc[i][j]);
    }
    __syncthreads();
    cur ^= 1;
  }
#pragma unroll
  for (int j = 0; j < 4; ++j) {
    const int gc = bj * 128 + wc * 64 + j * 16 + ln;
    const float bv = bias[gc];
#pragma unroll
    for (int i = 0; i < 4; ++i) {
      const int gr = bi * 128 + wr * 64 + i * 16 + kg * 4;
#pragma unroll
      for (int r = 0; r < 4; ++r)
        out[(size_t)(gr + r) * Cc + gc] = acc[i][j][r] + bv;
    }
  }
}

// ---------------------------------------------------------------------------
extern "C" void kernel_launch(void* const* d_in, const int* in_sizes, int n_in,
                              void* d_out, int out_size, void* d_ws,
                              size_t ws_size, hipStream_t stream) {
  const float* x = (const float*)d_in[0];
  const float* qkv_w = (const float*)d_in[1];
  const float* proj_w = (const float*)d_in[2];
  const float* proj_b = (const float*)d_in[3];
  const float* rand_matrix = (const float*)d_in[4];
  const float* learned_k = (const float*)d_in[5];
  const float* learned_lam = (const float*)d_in[6];
  const float* learned_L = (const float*)d_in[7];
  float* out = (float*)d_out;

  const size_t SX = 25165824;   // x_bf / attn_bf (aliased)
  const size_t SQF = 50331648;  // qf_t
  const size_t SVT = 25165824;  // vb_t
  const size_t SXT = 3145728;   // xss_t
  const size_t SW = 1179648;    // w_bf
  const size_t SPW = 589824;    // pw_bf
  const size_t SRT = 98304;     // rand_t
  const size_t U16TOT = SX + SQF + SVT + SXT + SW + SPW + SRT;
  const size_t SKK = 6291456, SIN = 3145728;
  const size_t need = U16TOT * 2 + (SKK + SIN) * 4;
  if (ws_size < need) return;  // graceful fail rather than OOB crash

  u16* xbf = (u16*)d_ws;
  u16* qft = xbf + SX;
  u16* vbt = qft + SQF;
  u16* xsst = vbt + SVT;
  u16* wbf = xsst + SXT;
  u16* pwbf = wbf + SW;
  u16* randt = pwbf + SPW;
  float* kkf = (float*)(randt + SRT);
  float* inpf = kkf + SKK;
  u16* attnbf = xbf;  // alias: x_bf dead after qkv

  prep_kernel<<<2048, 256, 0, stream>>>(x, qkv_w, proj_w, rand_matrix, xbf,
                                        wbf, pwbf, randt);
  qkv_qf_kernel<<<3072, 256, 0, stream>>>(xbf, wbf, randt, qft, vbt);
  kk_inp_kernel<<<Bc * Hc, 384, 0, stream>>>(qft, vbt, kkf, inpf);
  solve_kernel<<<Bc * Hc, 256, 0, stream>>>(kkf, inpf, learned_k, learned_lam,
                                            learned_L, xsst);
  pvout_kernel<<<dim3(Bc * Hc, Nc / 128), 256, 0, stream>>>(qft, xsst, attnbf);
  proj_kernel<<<1536, 256, 0, stream>>>(attnbf, pwbf, proj_b, out);
}

// Round 8
// 398.762 us; speedup vs baseline: 1.9953x; 1.4802x over previous
//
#include <hip/hip_runtime.h>
#include <math.h>

typedef unsigned short u16;
typedef unsigned int u32;
typedef _Float16 f16;
typedef __attribute__((ext_vector_type(8))) short bf16x8;
typedef __attribute__((ext_vector_type(8))) _Float16 f16x8;
typedef __attribute__((ext_vector_type(4))) float f32x4;

constexpr int Bc = 32, Nc = 1024, Cc = 768, Hc = 12, HDc = 64, Mc = 128;
constexpr int NUM_STEP_C = 8;
constexpr float QSCALE = 0.35355339059327376f;      // 8^-0.5
constexpr float INV_SQRT_M = 0.088388347648318447f; // 1/sqrt(128)
constexpr float EPSC = 1e-12f;
constexpr int FS = 136;  // f16 LDS row stride (16B-aligned, banks +4 mod 32)

__device__ __forceinline__ float softf(float z, float thr) {
  float az = fabsf(z) - thr;
  float g = 0.5f * az * (1.0f + erff(az * 0.70710678118654752f));
  return (z > 0.f) ? g : ((z < 0.f) ? -g : 0.f);
}

__device__ __forceinline__ u16 f2bf(float f) {
  u32 u = __float_as_uint(f);
  u += 0x7fffu + ((u >> 16) & 1u);
  return (u16)(u >> 16);
}

__device__ __forceinline__ f32x4 fzero() {
  f32x4 z; z[0] = 0.f; z[1] = 0.f; z[2] = 0.f; z[3] = 0.f; return z;
}

__device__ __forceinline__ f32x4 mfma16(bf16x8 a, bf16x8 b, f32x4 c) {
  return __builtin_amdgcn_mfma_f32_16x16x32_bf16(a, b, c, 0, 0, 0);
}
__device__ __forceinline__ f32x4 mfma16h(f16x8 a, f16x8 b, f32x4 c) {
  return __builtin_amdgcn_mfma_f32_16x16x32_f16(a, b, c, 0, 0, 0);
}

// Swizzled read offset within a [*][64]-u16 LDS tile: col(u16) XOR'ed by row
#define SWZ_COL(col, row) ((col) ^ (((row) & 7) << 3))

// Stage 32 rows x 64 u16 of a row-major (ld elems) global tile into linear
// LDS [.][64]; inverse swizzle pre-applied to the GLOBAL source (rule #21).
__device__ __forceinline__ void stage_swz(const u16* __restrict__ g, int ld,
                                          u16* lds, int w, int lane) {
  const int rr = lane >> 3;                 // 0..7 row within 8-row call
  const int cs = ((lane & 7) ^ rr) << 3;    // pre-swizzled col (u16)
#pragma unroll
  for (int c = 0; c < 4; ++c) {
    const int r0 = w * 32 + c * 8;
    __builtin_amdgcn_global_load_lds(
        (const __attribute__((address_space(1))) void*)(g + (size_t)(r0 + rr) * ld + cs),
        (__attribute__((address_space(3))) void*)(lds + r0 * 64), 16, 0, 0);
  }
}

// ---------------------------------------------------------------------------
// prep: f32 -> bf16 (x, qkv_w, proj_w), rand_matrix transpose, and
// learned_k -> fp16 (direct + transposed)
// ---------------------------------------------------------------------------
__global__ __launch_bounds__(256) void prep_kernel(
    const float* __restrict__ x, const float* __restrict__ qw,
    const float* __restrict__ pw, const float* __restrict__ rnd,
    const float* __restrict__ lkf, u16* __restrict__ xbf,
    u16* __restrict__ wbf, u16* __restrict__ pwbf, u16* __restrict__ randt,
    f16* __restrict__ lk16, f16* __restrict__ lkT16) {
  const int NX8 = 3145728, NW8 = 147456, NP8 = 73728, NR = 98304;
  const int NK8 = 2048, NKT = 16384;
  const int total = NX8 + NW8 + NP8 + NR + NK8 + NKT;
  for (int idx = blockIdx.x * 256 + threadIdx.x; idx < total;
       idx += gridDim.x * 256) {
    if (idx < NX8 + NW8 + NP8) {
      const float* src; u16* dst; int k;
      if (idx < NX8) { src = x; dst = xbf; k = idx; }
      else if (idx < NX8 + NW8) { src = qw; dst = wbf; k = idx - NX8; }
      else { src = pw; dst = pwbf; k = idx - NX8 - NW8; }
      float4 a = *(const float4*)(src + (size_t)k * 8);
      float4 b = *(const float4*)(src + (size_t)k * 8 + 4);
      uint4 o;
      o.x = (u32)f2bf(a.x) | ((u32)f2bf(a.y) << 16);
      o.y = (u32)f2bf(a.z) | ((u32)f2bf(a.w) << 16);
      o.z = (u32)f2bf(b.x) | ((u32)f2bf(b.y) << 16);
      o.w = (u32)f2bf(b.z) | ((u32)f2bf(b.w) << 16);
      *(uint4*)(dst + (size_t)k * 8) = o;
    } else if (idx < NX8 + NW8 + NP8 + NR) {
      int k = idx - NX8 - NW8 - NP8;           // rand_t[h][m][d]
      int h = k >> 13, rem = k & 8191, m = rem >> 6, d = rem & 63;
      randt[k] = f2bf(rnd[(size_t)h * 8192 + d * 128 + m]);
    } else if (idx < NX8 + NW8 + NP8 + NR + NK8) {
      int k = idx - (NX8 + NW8 + NP8 + NR);    // 8-wide fp16 convert
      float4 a = *(const float4*)(lkf + (size_t)k * 8);
      float4 b = *(const float4*)(lkf + (size_t)k * 8 + 4);
      union { f16 h[8]; uint4 u; } z;
      z.h[0] = (f16)a.x; z.h[1] = (f16)a.y; z.h[2] = (f16)a.z; z.h[3] = (f16)a.w;
      z.h[4] = (f16)b.x; z.h[5] = (f16)b.y; z.h[6] = (f16)b.z; z.h[7] = (f16)b.w;
      *(uint4*)(lk16 + (size_t)k * 8) = z.u;
    } else {
      int k = idx - (NX8 + NW8 + NP8 + NR + NK8);  // lkT16[c][p] = lk[p][c]
      int c = k >> 7, p = k & 127;
      lkT16[k] = (f16)lkf[p * 128 + c];
    }
  }
}

// ---------------------------------------------------------------------------
// Fused QKV MFMA GEMM + qf epilogue. BK=64, 2-phase dbuf, XCD swizzle.
// bj<6: q -> qf_t (bf16 [B,H,M,N]); bj>=6: v -> vb_t (bf16 [B,H,HD,N]).
// ---------------------------------------------------------------------------
__global__ __launch_bounds__(256) void qkv_qf_kernel(
    const u16* __restrict__ xbf, const u16* __restrict__ wbf,
    const u16* __restrict__ randt, u16* __restrict__ qft,
    u16* __restrict__ vbt) {
  __shared__ __align__(16) u16 SH[32768];
  const int t = threadIdx.x;
  const int hblk = blockIdx.x;
  const int lin = (hblk & 7) * 384 + (hblk >> 3);
  const int bi = lin / 12, bj = lin % 12;
  const int w = t >> 6, lane = t & 63, ln = lane & 15, kg = lane >> 4;
  const int wr = w >> 1, wc = w & 1;
  f32x4 acc[4][4];
#pragma unroll
  for (int i = 0; i < 4; ++i)
#pragma unroll
    for (int j = 0; j < 4; ++j) acc[i][j] = fzero();
  const u16* Ag = xbf + (size_t)(bi * 128) * Cc;
  const u16* Bg = wbf + (size_t)(bj * 128) * Cc;
  stage_swz(Ag, Cc, SH, w, lane);
  stage_swz(Bg, Cc, SH + 8192, w, lane);
  __syncthreads();
  int cur = 0;
  for (int tt = 0; tt < 12; ++tt) {
    if (tt < 11) {
      stage_swz(Ag + (tt + 1) * 64, Cc, SH + (cur ^ 1) * 16384, w, lane);
      stage_swz(Bg + (tt + 1) * 64, Cc, SH + 8192 + (cur ^ 1) * 16384, w, lane);
    }
    const u16* Als = SH + cur * 16384;
    const u16* Bls = SH + 8192 + cur * 16384;
#pragma unroll
    for (int ks = 0; ks < 2; ++ks) {
      const int cb = ks * 32 + kg * 8;
      bf16x8 af[4], bf[4];
#pragma unroll
      for (int i = 0; i < 4; ++i)
        af[i] = *(const bf16x8*)(Als + (wr * 64 + i * 16 + ln) * 64 +
                                 SWZ_COL(cb, ln));
#pragma unroll
      for (int j = 0; j < 4; ++j)
        bf[j] = *(const bf16x8*)(Bls + (wc * 64 + j * 16 + ln) * 64 +
                                 SWZ_COL(cb, ln));
#pragma unroll
      for (int i = 0; i < 4; ++i)
#pragma unroll
        for (int j = 0; j < 4; ++j) acc[i][j] = mfma16(af[i], bf[j], acc[i][j]);
    }
    __syncthreads();
    cur ^= 1;
  }
  const int b = bi >> 3;
  const int ntile = (bi & 7) * 128;
  if (bj >= 6) {
    const int h = (bj - 6) * 2 + wc;
    u16* vt = vbt + ((size_t)(b * Hc + h) * 64) * 1024;
#pragma unroll
    for (int i = 0; i < 4; ++i)
#pragma unroll
      for (int j = 0; j < 4; ++j) {
        int d = j * 16 + ln;
        int n0 = ntile + wr * 64 + i * 16 + kg * 4;
        uint2 pv;
        pv.x = (u32)f2bf(acc[i][j][0]) | ((u32)f2bf(acc[i][j][1]) << 16);
        pv.y = (u32)f2bf(acc[i][j][2]) | ((u32)f2bf(acc[i][j][3]) << 16);
        *(uint2*)(vt + (size_t)d * 1024 + n0) = pv;
      }
  } else {
#pragma unroll
    for (int i = 0; i < 4; ++i)
#pragma unroll
      for (int j = 0; j < 4; ++j) acc[i][j] *= QSCALE;
    float hn[4][4];
#pragma unroll
    for (int i = 0; i < 4; ++i)
#pragma unroll
      for (int r = 0; r < 4; ++r) {
        float s = acc[i][0][r] * acc[i][0][r] + acc[i][1][r] * acc[i][1][r] +
                  acc[i][2][r] * acc[i][2][r] + acc[i][3][r] * acc[i][3][r];
        s += __shfl_xor(s, 1); s += __shfl_xor(s, 2);
        s += __shfl_xor(s, 4); s += __shfl_xor(s, 8);
        hn[i][r] = 0.5f * s;
      }
    u16* Qls = SH;
#pragma unroll
    for (int i = 0; i < 4; ++i)
#pragma unroll
      for (int j = 0; j < 4; ++j)
#pragma unroll
        for (int r = 0; r < 4; ++r)
          Qls[(size_t)(wc * 128 + wr * 64 + i * 16 + kg * 4 + r) * 72 +
              j * 16 + ln] = f2bf(acc[i][j][r]);
    __syncthreads();
    const int hq = bj * 2 + (w & 1);
    const int r0q = (w >> 1) * 64;
    const u16* rt = randt + (size_t)hq * Mc * HDc;  // [m][64]
    u16* qtb = qft + ((size_t)(b * Hc + hq) * Mc) * Nc;  // [m][n]
    const u16* qsl = Qls + (size_t)(w & 1) * 128 * 72;
#pragma unroll
    for (int mh = 0; mh < 2; ++mh) {
      f32x4 a2[4][4];
#pragma unroll
      for (int i = 0; i < 4; ++i)
#pragma unroll
        for (int j = 0; j < 4; ++j) a2[i][j] = fzero();
#pragma unroll
      for (int ks = 0; ks < 2; ++ks) {
        bf16x8 af[4], bfr[4];
#pragma unroll
        for (int i = 0; i < 4; ++i)
          af[i] = *(const bf16x8*)(qsl + (size_t)(r0q + i * 16 + ln) * 72 +
                                   ks * 32 + kg * 8);
#pragma unroll
        for (int j = 0; j < 4; ++j)
          bfr[j] = *(const bf16x8*)(rt +
                                    (size_t)(mh * 64 + j * 16 + ln) * 64 +
                                    ks * 32 + kg * 8);
#pragma unroll
        for (int i = 0; i < 4; ++i)
#pragma unroll
          for (int j = 0; j < 4; ++j)
            a2[i][j] = mfma16(af[i], bfr[j], a2[i][j]);
      }
#pragma unroll
      for (int i = 0; i < 4; ++i)
#pragma unroll
        for (int j = 0; j < 4; ++j) {
          const int m = mh * 64 + j * 16 + ln;
          const int n0 = ntile + r0q + i * 16 + kg * 4;
          float e0 = __expf(a2[i][j][0] - hn[i][0]) * INV_SQRT_M;
          float e1 = __expf(a2[i][j][1] - hn[i][1]) * INV_SQRT_M;
          float e2 = __expf(a2[i][j][2] - hn[i][2]) * INV_SQRT_M;
          float e3 = __expf(a2[i][j][3] - hn[i][3]) * INV_SQRT_M;
          uint2 pv;
          pv.x = (u32)f2bf(e0) | ((u32)f2bf(e1) << 16);
          pv.y = (u32)f2bf(e2) | ((u32)f2bf(e3) << 16);
          *(uint2*)(qtb + (size_t)m * Nc + n0) = pv;
        }
    }
  }
}

// ---------------------------------------------------------------------------
// kk_inp: per bh, C[128 x 192] = qf_t . [qf_t | vbt]^T over n (K = 1024).
// 2-phase double-buffered staging. 384 thr, 6 waves.
// ---------------------------------------------------------------------------
__global__ __launch_bounds__(384) void kk_inp_kernel(
    const u16* __restrict__ qft, const u16* __restrict__ vbt,
    float* __restrict__ kk, float* __restrict__ inp) {
  __shared__ __align__(16) u16 SH[24576];
  const int t = threadIdx.x, bh = blockIdx.x;
  const int w = t >> 6, lane = t & 63, ln = lane & 15, kg = lane >> 4;
  const int wr = w / 3, wc = w % 3;
  const u16* qg = qft + (size_t)bh * Mc * Nc;   // [m][n]
  const u16* vg = vbt + (size_t)bh * 64 * Nc;   // [d][n]
  const int rr = lane >> 3;
  const int cs = ((lane & 7) ^ rr) << 3;
  f32x4 acc[4][4];
#pragma unroll
  for (int i = 0; i < 4; ++i)
#pragma unroll
    for (int j = 0; j < 4; ++j) acc[i][j] = fzero();

  auto stage = [&](int kt, int buf) {
    u16* Atl = SH + buf * 12288;
    u16* Vtl = Atl + 8192;
    const int n0 = kt * 64;
#pragma unroll
    for (int q = 0; q < 4; ++q) {
      const int idx = w * 4 + q;
      if (idx < 16) {
        __builtin_amdgcn_global_load_lds(
            (const __attribute__((address_space(1))) void*)(
                qg + (size_t)(idx * 8 + rr) * Nc + n0 + cs),
            (__attribute__((address_space(3))) void*)(Atl + idx * 8 * 64), 16,
            0, 0);
      } else {
        __builtin_amdgcn_global_load_lds(
            (const __attribute__((address_space(1))) void*)(
                vg + (size_t)((idx - 16) * 8 + rr) * Nc + n0 + cs),
            (__attribute__((address_space(3))) void*)(Vtl + (idx - 16) * 8 * 64),
            16, 0, 0);
      }
    }
  };

  stage(0, 0);
  __syncthreads();
  int cur = 0;
  for (int kt = 0; kt < 16; ++kt) {
    if (kt < 15) stage(kt + 1, cur ^ 1);
    const u16* Atl = SH + cur * 12288;
    const u16* Vtl = Atl + 8192;
#pragma unroll
    for (int ks = 0; ks < 2; ++ks) {
      const int cb = ks * 32 + kg * 8;
      bf16x8 af[4], bf[4];
#pragma unroll
      for (int i = 0; i < 4; ++i)
        af[i] = *(const bf16x8*)(Atl + (wr * 64 + i * 16 + ln) * 64 +
                                 SWZ_COL(cb, ln));
      if (wc < 2) {
#pragma unroll
        for (int j = 0; j < 4; ++j)
          bf[j] = *(const bf16x8*)(Atl + (wc * 64 + j * 16 + ln) * 64 +
                                   SWZ_COL(cb, ln));
      } else {
#pragma unroll
        for (int j = 0; j < 4; ++j)
          bf[j] = *(const bf16x8*)(Vtl + (j * 16 + ln) * 64 + SWZ_COL(cb, ln));
      }
#pragma unroll
      for (int i = 0; i < 4; ++i)
#pragma unroll
        for (int j = 0; j < 4; ++j) acc[i][j] = mfma16(af[i], bf[j], acc[i][j]);
    }
    __syncthreads();
    cur ^= 1;
  }
  if (wc < 2) {
    float* og = kk + (size_t)bh * Mc * Mc;
#pragma unroll
    for (int i = 0; i < 4; ++i)
#pragma unroll
      for (int j = 0; j < 4; ++j)
#pragma unroll
        for (int r = 0; r < 4; ++r)
          og[(size_t)(wr * 64 + i * 16 + kg * 4 + r) * Mc + wc * 64 + j * 16 +
             ln] = acc[i][j][r];
  } else {
    float* og = inp + (size_t)bh * Mc * HDc;
#pragma unroll
    for (int i = 0; i < 4; ++i)
#pragma unroll
      for (int j = 0; j < 4; ++j)
#pragma unroll
        for (int r = 0; r < 4; ++r)
          og[(size_t)(wr * 64 + i * 16 + kg * 4 + r) * HDc + j * 16 + ln] =
              acc[i][j][r];
  }
}

// ---------------------------------------------------------------------------
// solve: fused norm + kkl + ISTA, one block per (b,h), fp16 MFMA.
// A1: kkn -> T1^T -> xs^T ; B1: K^T -> K -> kk_l. State xr/ri in f32 regs.
// Writes xss_t bf16 [B,H,64,128].
// ---------------------------------------------------------------------------
__global__ __launch_bounds__(256) void solve_kernel(
    const float* __restrict__ kk, const float* __restrict__ inp,
    const f16* __restrict__ lk16, const f16* __restrict__ lkT16,
    const float* __restrict__ lamp, const float* __restrict__ Lp,
    u16* __restrict__ xsst) {
  __shared__ __align__(16) f16 A1[128 * FS];
  __shared__ __align__(16) f16 B1[128 * FS];
  __shared__ float nrm[128], inr[128];
  __shared__ float rsum2[256];
  __shared__ float Lsh;
  const int t = threadIdx.x, bh = blockIdx.x;
  const int w = t >> 6, lane = t & 63, ln = lane & 15, kq = lane >> 4;
  const float* kkg = kk + (size_t)bh * 16384;
  if (t < 128) {
    float nm = fmaxf(sqrtf(kkg[t * 128 + t]), EPSC);
    nrm[t] = nm;
    inr[t] = 1.0f / nm;
  }
  // stage K^T -> B1
#pragma unroll
  for (int c = 0; c < 8; ++c) {
    int ch = c * 256 + t;
    int r = ch >> 4, q8 = (ch & 15) * 8;
    *(uint4*)&B1[r * FS + q8] = *(const uint4*)&lkT16[r * 128 + q8];
  }
  __syncthreads();
  // kkn (normalized) fp16 -> A1
#pragma unroll
  for (int c = 0; c < 16; ++c) {
    int ch = c * 256 + t;
    int m = ch >> 5, p4 = (ch & 31) * 4;
    float4 v = *(const float4*)&kkg[m * 128 + p4];
    float im = inr[m];
    union { f16 h[4]; uint2 u; } z;
    z.h[0] = (f16)(v.x * im * inr[p4]);
    z.h[1] = (f16)(v.y * im * inr[p4 + 1]);
    z.h[2] = (f16)(v.z * im * inr[p4 + 2]);
    z.h[3] = (f16)(v.w * im * inr[p4 + 3]);
    *(uint2*)&A1[m * FS + p4] = z.u;
  }
  __syncthreads();
  // L = max_m sum_p |kkn| + 1 (two half-rows per thread)
  {
    const int m = t & 127, hf = (t >> 7) * 64;
    float s = 0.f;
#pragma unroll 8
    for (int p = 0; p < 64; ++p) s += fabsf((float)A1[m * FS + hf + p]);
    rsum2[t] = s;
  }
  // pass 1: T1 = kkn . K   (A = A1 rows p, B = B1 = K^T rows r)
  f32x4 t1a[2][8];
#pragma unroll
  for (int i = 0; i < 2; ++i)
#pragma unroll
    for (int j = 0; j < 8; ++j) t1a[i][j] = fzero();
  __syncthreads();  // rsum2 ready; A1/B1 stable
  if (t == 0) {
    float mx = 0.f;
    for (int i = 0; i < 128; ++i) mx = fmaxf(mx, rsum2[i] + rsum2[i + 128]);
    Lsh = mx + 1.0f;
  }
#pragma unroll
  for (int ks = 0; ks < 4; ++ks) {
    f16x8 a[2], b[8];
#pragma unroll
    for (int i = 0; i < 2; ++i)
      a[i] = *(const f16x8*)&A1[(w * 32 + i * 16 + ln) * FS + ks * 32 + kq * 8];
#pragma unroll
    for (int j = 0; j < 8; ++j)
      b[j] = *(const f16x8*)&B1[(j * 16 + ln) * FS + ks * 32 + kq * 8];
#pragma unroll
    for (int i = 0; i < 2; ++i)
#pragma unroll
      for (int j = 0; j < 8; ++j) t1a[i][j] = mfma16h(a[i], b[j], t1a[i][j]);
  }
  __syncthreads();
  // T1^T -> A1 ; K -> B1
#pragma unroll
  for (int i = 0; i < 2; ++i)
#pragma unroll
    for (int j = 0; j < 8; ++j) {
      const int r = j * 16 + ln, p0 = w * 32 + i * 16 + kq * 4;
      union { f16 h[4]; uint2 u; } z;
      z.h[0] = (f16)t1a[i][j][0]; z.h[1] = (f16)t1a[i][j][1];
      z.h[2] = (f16)t1a[i][j][2]; z.h[3] = (f16)t1a[i][j][3];
      *(uint2*)&A1[r * FS + p0] = z.u;
    }
#pragma unroll
  for (int c = 0; c < 8; ++c) {
    int ch = c * 256 + t;
    int r = ch >> 4, q8 = (ch & 15) * 8;
    *(uint4*)&B1[r * FS + q8] = *(const uint4*)&lk16[r * 128 + q8];
  }
  __syncthreads();
  // pass 2: kk_l = K . T1   (A = B1 = K rows m, B = A1 = T1^T rows r)
  f32x4 kla[2][8];
#pragma unroll
  for (int i = 0; i < 2; ++i)
#pragma unroll
    for (int j = 0; j < 8; ++j) kla[i][j] = fzero();
#pragma unroll
  for (int ks = 0; ks < 4; ++ks) {
    f16x8 a[2], b[8];
#pragma unroll
    for (int i = 0; i < 2; ++i)
      a[i] = *(const f16x8*)&B1[(w * 32 + i * 16 + ln) * FS + ks * 32 + kq * 8];
#pragma unroll
    for (int j = 0; j < 8; ++j)
      b[j] = *(const f16x8*)&A1[(j * 16 + ln) * FS + ks * 32 + kq * 8];
#pragma unroll
    for (int i = 0; i < 2; ++i)
#pragma unroll
      for (int j = 0; j < 8; ++j) kla[i][j] = mfma16h(a[i], b[j], kla[i][j]);
  }
  __syncthreads();
  // kks (kk_l fp16) -> B1 [m][r]
#pragma unroll
  for (int i = 0; i < 2; ++i)
#pragma unroll
    for (int j = 0; j < 8; ++j)
#pragma unroll
      for (int r = 0; r < 4; ++r)
        B1[(w * 32 + i * 16 + kq * 4 + r) * FS + j * 16 + ln] =
            (f16)kla[i][j][r];
  // ---- ISTA ----
  const float lam = lamp[0] * 0.1f;
  const float Ll = Lsh / Lp[0];
  const float thr = lam / Ll;
  const float invLl = 1.0f / Ll;
  const float* ig = inp + (size_t)bh * 8192;
  float ri[2][4][4], xr[2][4][4];
#pragma unroll
  for (int i = 0; i < 2; ++i)
#pragma unroll
    for (int j = 0; j < 4; ++j)
#pragma unroll
      for (int r = 0; r < 4; ++r) {
        const int m = w * 32 + i * 16 + kq * 4 + r;
        const int d = j * 16 + ln;
        ri[i][j][r] = ig[m * 64 + d] * inr[m];
        xr[i][j][r] = softf(ri[i][j][r], lam);
      }
  __syncthreads();  // kks writes + pass2 A1 reads complete
  // xs^T -> A1 [d][m]
#pragma unroll
  for (int i = 0; i < 2; ++i)
#pragma unroll
    for (int j = 0; j < 4; ++j) {
      const int d = j * 16 + ln, m0 = w * 32 + i * 16 + kq * 4;
      union { f16 h[4]; uint2 u; } z;
      z.h[0] = (f16)xr[i][j][0]; z.h[1] = (f16)xr[i][j][1];
      z.h[2] = (f16)xr[i][j][2]; z.h[3] = (f16)xr[i][j][3];
      *(uint2*)&A1[d * FS + m0] = z.u;
    }
  __syncthreads();
  for (int s = 0; s < NUM_STEP_C; ++s) {
    f32x4 acc[2][4];
#pragma unroll
    for (int i = 0; i < 2; ++i)
#pragma unroll
      for (int j = 0; j < 4; ++j) acc[i][j] = fzero();
#pragma unroll
    for (int ks = 0; ks < 4; ++ks) {
      f16x8 a[2], b[4];
#pragma unroll
      for (int i = 0; i < 2; ++i)
        a[i] = *(const f16x8*)&B1[(w * 32 + i * 16 + ln) * FS + ks * 32 + kq * 8];
#pragma unroll
      for (int j = 0; j < 4; ++j)
        b[j] = *(const f16x8*)&A1[(j * 16 + ln) * FS + ks * 32 + kq * 8];
#pragma unroll
      for (int i = 0; i < 2; ++i)
#pragma unroll
        for (int j = 0; j < 4; ++j) acc[i][j] = mfma16h(a[i], b[j], acc[i][j]);
    }
#pragma unroll
    for (int i = 0; i < 2; ++i)
#pragma unroll
      for (int j = 0; j < 4; ++j)
#pragma unroll
        for (int r = 0; r < 4; ++r)
          xr[i][j][r] =
              softf(xr[i][j][r] - (acc[i][j][r] - ri[i][j][r]) * invLl, thr);
    __syncthreads();
#pragma unroll
    for (int i = 0; i < 2; ++i)
#pragma unroll
      for (int j = 0; j < 4; ++j) {
        const int d = j * 16 + ln, m0 = w * 32 + i * 16 + kq * 4;
        union { f16 h[4]; uint2 u; } z;
        z.h[0] = (f16)xr[i][j][0]; z.h[1] = (f16)xr[i][j][1];
        z.h[2] = (f16)xr[i][j][2]; z.h[3] = (f16)xr[i][j][3];
        *(uint2*)&A1[d * FS + m0] = z.u;
      }
    __syncthreads();
  }
  // xss_t[d][m] bf16 = xr / nrm[m]
  u16* og = xsst + (size_t)bh * 8192;
#pragma unroll
  for (int i = 0; i < 2; ++i)
#pragma unroll
    for (int j = 0; j < 4; ++j) {
      const int d = j * 16 + ln, m0 = w * 32 + i * 16 + kq * 4;
      uint2 pv;
      pv.x = (u32)f2bf(xr[i][j][0] * inr[m0]) |
             ((u32)f2bf(xr[i][j][1] * inr[m0 + 1]) << 16);
      pv.y = (u32)f2bf(xr[i][j][2] * inr[m0 + 2]) |
             ((u32)f2bf(xr[i][j][3] * inr[m0 + 3]) << 16);
      *(uint2*)&og[d * 128 + m0] = pv;
    }
}

// ---------------------------------------------------------------------------
// pvout: attn_bf[b*N+n][h*64+d] = sum_m qf_t[bh][m][n] * xss_t[bh][d][m]
// ---------------------------------------------------------------------------
__global__ __launch_bounds__(256) void pvout_kernel(
    const u16* __restrict__ qft, const u16* __restrict__ xsst,
    u16* __restrict__ attn) {
  const int t = threadIdx.x;
  const int bh = blockIdx.x, nt = blockIdx.y;
  const int b = bh / Hc, h = bh % Hc;
  const int w = t >> 6, lane = t & 63, ln = lane & 15, kg = lane >> 4;
  const u16* qt = qft + (size_t)bh * Mc * Nc;   // [m][n]
  const u16* xg = xsst + (size_t)bh * HDc * Mc; // [d][m]
  f32x4 acc[2][4];
#pragma unroll
  for (int i = 0; i < 2; ++i)
#pragma unroll
    for (int j = 0; j < 4; ++j) acc[i][j] = fzero();
#pragma unroll
  for (int ks = 0; ks < 4; ++ks) {
    const int m8 = ks * 32 + kg * 8;
    bf16x8 af[2];
#pragma unroll
    for (int i = 0; i < 2; ++i) {
      const int n = nt * 128 + w * 32 + i * 16 + ln;
      const u16* p = qt + (size_t)m8 * Nc + n;
#pragma unroll
      for (int e = 0; e < 8; ++e) af[i][e] = (short)p[(size_t)e * Nc];
    }
    bf16x8 bf[4];
#pragma unroll
    for (int j = 0; j < 4; ++j)
      bf[j] = *(const bf16x8*)(xg + (size_t)(j * 16 + ln) * Mc + m8);
#pragma unroll
    for (int i = 0; i < 2; ++i)
#pragma unroll
      for (int j = 0; j < 4; ++j) acc[i][j] = mfma16(af[i], bf[j], acc[i][j]);
  }
#pragma unroll
  for (int i = 0; i < 2; ++i)
#pragma unroll
    for (int j = 0; j < 4; ++j)
#pragma unroll
      for (int r = 0; r < 4; ++r) {
        int n = nt * 128 + w * 32 + i * 16 + kg * 4 + r;
        attn[((size_t)(b * Nc + n)) * Cc + h * 64 + j * 16 + ln] =
            f2bf(acc[i][j][r]);
      }
}

// ---------------------------------------------------------------------------
// proj: out[i][j] = sum_k attn_bf[i][k] * pwbf[j][k] + bias[j]  (f32 out)
// ---------------------------------------------------------------------------
__global__ __launch_bounds__(256) void proj_kernel(
    const u16* __restrict__ abf, const u16* __restrict__ pwbf,
    const float* __restrict__ bias, float* __restrict__ out) {
  __shared__ __align__(16) u16 SH[32768];
  const int t = threadIdx.x;
  const int hblk = blockIdx.x;
  const int lin = (hblk & 7) * 192 + (hblk >> 3);
  const int bi = lin / 6, bj = lin % 6;
  const int w = t >> 6, lane = t & 63, ln = lane & 15, kg = lane >> 4;
  const int wr = w >> 1, wc = w & 1;
  f32x4 acc[4][4];
#pragma unroll
  for (int i = 0; i < 4; ++i)
#pragma unroll
    for (int j = 0; j < 4; ++j) acc[i][j] = fzero();
  const u16* Ag = abf + (size_t)(bi * 128) * Cc;
  const u16* Bg = pwbf + (size_t)(bj * 128) * Cc;
  stage_swz(Ag, Cc, SH, w, lane);
  stage_swz(Bg, Cc, SH + 8192, w, lane);
  __syncthreads();
  int cur = 0;
  for (int tt = 0; tt < 12; ++tt) {
    if (tt < 11) {
      stage_swz(Ag + (tt + 1) * 64, Cc, SH + (cur ^ 1) * 16384, w, lane);
      stage_swz(Bg + (tt + 1) * 64, Cc, SH + 8192 + (cur ^ 1) * 16384, w, lane);
    }
    const u16* Als = SH + cur * 16384;
    const u16* Bls = SH + 8192 + cur * 16384;
#pragma unroll
    for (int ks = 0; ks < 2; ++ks) {
      const int cb = ks * 32 + kg * 8;
      bf16x8 af[4], bf[4];
#pragma unroll
      for (int i = 0; i < 4; ++i)
        af[i] = *(const bf16x8*)(Als + (wr * 64 + i * 16 + ln) * 64 +
                                 SWZ_COL(cb, ln));
#pragma unroll
      for (int j = 0; j < 4; ++j)
        bf[j] = *(const bf16x8*)(Bls + (wc * 64 + j * 16 + ln) * 64 +
                                 SWZ_COL(cb, ln));
#pragma unroll
      for (int i = 0; i < 4; ++i)
#pragma unroll
        for (int j = 0; j < 4; ++j) acc[i][j] = mfma16(af[i], bf[j], acc[i][j]);
    }
    __syncthreads();
    cur ^= 1;
  }
#pragma unroll
  for (int j = 0; j < 4; ++j) {
    const int gc = bj * 128 + wc * 64 + j * 16 + ln;
    const float bv = bias[gc];
#pragma unroll
    for (int i = 0; i < 4; ++i) {
      const int gr = bi * 128 + wr * 64 + i * 16 + kg * 4;
#pragma unroll
      for (int r = 0; r < 4; ++r)
        out[(size_t)(gr + r) * Cc + gc] = acc[i][j][r] + bv;
    }
  }
}

// ---------------------------------------------------------------------------
extern "C" void kernel_launch(void* const* d_in, const int* in_sizes, int n_in,
                              void* d_out, int out_size, void* d_ws,
                              size_t ws_size, hipStream_t stream) {
  const float* x = (const float*)d_in[0];
  const float* qkv_w = (const float*)d_in[1];
  const float* proj_w = (const float*)d_in[2];
  const float* proj_b = (const float*)d_in[3];
  const float* rand_matrix = (const float*)d_in[4];
  const float* learned_k = (const float*)d_in[5];
  const float* learned_lam = (const float*)d_in[6];
  const float* learned_L = (const float*)d_in[7];
  float* out = (float*)d_out;

  const size_t SX = 25165824;   // x_bf / attn_bf (aliased)
  const size_t SQF = 50331648;  // qf_t
  const size_t SVT = 25165824;  // vb_t
  const size_t SXT = 3145728;   // xss_t
  const size_t SW = 1179648;    // w_bf
  const size_t SPW = 589824;    // pw_bf
  const size_t SRT = 98304;     // rand_t
  const size_t SLK = 16384;     // lk16 / lkT16 (f16, counted as u16 elems)
  const size_t U16TOT = SX + SQF + SVT + SXT + SW + SPW + SRT + 2 * SLK;
  const size_t SKK = 6291456, SIN = 3145728;
  const size_t need = U16TOT * 2 + (SKK + SIN) * 4;
  if (ws_size < need) return;  // graceful fail rather than OOB crash

  u16* xbf = (u16*)d_ws;
  u16* qft = xbf + SX;
  u16* vbt = qft + SQF;
  u16* xsst = vbt + SVT;
  u16* wbf = xsst + SXT;
  u16* pwbf = wbf + SW;
  u16* randt = pwbf + SPW;
  f16* lk16 = (f16*)(randt + SRT);
  f16* lkT16 = lk16 + SLK;
  float* kkf = (float*)(lkT16 + SLK);
  float* inpf = kkf + SKK;
  u16* attnbf = xbf;  // alias: x_bf dead after qkv

  prep_kernel<<<2048, 256, 0, stream>>>(x, qkv_w, proj_w, rand_matrix,
                                        learned_k, xbf, wbf, pwbf, randt,
                                        lk16, lkT16);
  qkv_qf_kernel<<<3072, 256, 0, stream>>>(xbf, wbf, randt, qft, vbt);
  kk_inp_kernel<<<Bc * Hc, 384, 0, stream>>>(qft, vbt, kkf, inpf);
  solve_kernel<<<Bc * Hc, 256, 0, stream>>>(kkf, inpf, lk16, lkT16,
                                            learned_lam, learned_L, xsst);
  pvout_kernel<<<dim3(Bc * Hc, Nc / 128), 256, 0, stream>>>(qft, xsst, attnbf);
  proj_kernel<<<1536, 256, 0, stream>>>(attnbf, pwbf, proj_b, out);
}